// Round 1
// 684.765 us; speedup vs baseline: 1.0640x; 1.0640x over previous
//
#include <hip/hip_runtime.h>

#define LRELU_SLOPE 0.01f
#define NEG_BIG -1e10f

typedef unsigned short ushort_t;
typedef __bf16 bf16x8 __attribute__((ext_vector_type(8)));
typedef float f32x4 __attribute__((ext_vector_type(4)));

static __device__ __forceinline__ float lrelu_f(float x) {
    return x >= 0.0f ? x : LRELU_SLOPE * x;
}

static __device__ __forceinline__ ushort_t f2bf(float f) {
    unsigned int u = __float_as_uint(f);
    u += 0x7fffu + ((u >> 16) & 1u);
    return (ushort_t)(u >> 16);
}

static __device__ __forceinline__ void gld_lds16(const ushort_t* g, ushort_t* l) {
    __builtin_amdgcn_global_load_lds((const __attribute__((address_space(1))) void*)g,
                                     (__attribute__((address_space(3))) void*)l,
                                     16, 0, 0);
}

// ---------------------------------------------------------------------------
// NT bf16 MFMA GEMM: C[m,n] = epi( sum_k A[m,k] * B[n,k] )
// 128x128 tile, 4 waves (2x2), BK=32, 16x16x32 MFMA.
// LDS layout XOR-swizzled: row r's k-chunk c (16B) stored at position
// c ^ ((r>>1)&3)  -> ds_read_b128 fragment reads are bank-conflict-free.
// Staging achieves this by permuting the global source chunk per lane
// (global_load_lds dest is fixed at lane*16B).
// XCD-aware tile remap: HW round-robins linear block id across the 8 XCD L2s;
// remap lin -> (lin%8)*(nwg/8)+lin/8 so each XCD owns a CONTIGUOUS tile range.
// The 4 column-tiles sharing an A row-panel then land on ONE XCD -> each A
// panel is fetched from HBM once instead of 4x. Bijective (all grids %8==0).
// RM mask: row < Mhalf ? rm1[row] : rm2[row-Mhalf]  (combined-M launches)
// PM mask: rm1[bz*M+row] && rm2[bz*N+col] else += NEG_BIG (batched score GEMM)
// TWOUT: also store bf16 transposed per-batch with slot swap:
//   CT[(((row>>9)+64)&127)*S + col*512 + (row&511)]  -> [r2mT | r1mT] order
// ---------------------------------------------------------------------------
template<bool BIAS, bool LRELU, bool RM, bool PM, bool BF16OUT, bool TWOUT>
__global__ __launch_bounds__(256)
void gemm_nt(const ushort_t* __restrict__ A0, const ushort_t* __restrict__ A1,
             int Ksplit, int lda0, int lda1,
             const ushort_t* __restrict__ B, int ldb,
             const float* __restrict__ bias,
             const int* __restrict__ rm1, const int* __restrict__ rm2,
             void* __restrict__ C, int ldc,
             ushort_t* __restrict__ CT, int Mhalf,
             int M, int N, int K,
             long sA, long sB, long sC)
{
    __shared__ ushort_t As[128 * 32];
    __shared__ ushort_t Bs[128 * 32];

    // XCD-aware block remap (see header comment)
    const unsigned nbx = gridDim.x, nby = gridDim.y;
    unsigned lin = blockIdx.x + nbx * (blockIdx.y + nby * blockIdx.z);
    const unsigned nwg = nbx * nby * gridDim.z;
    if ((nwg & 7u) == 0u)
        lin = (lin & 7u) * (nwg >> 3) + (lin >> 3);
    const unsigned bxs = lin % nbx;
    const unsigned t1  = lin / nbx;
    const unsigned bys = t1 % nby;
    const unsigned bzs = t1 / nby;

    const int bz   = (int)bzs;
    const int tid  = threadIdx.x;
    const int w    = tid >> 6;
    const int lane = tid & 63;
    const int wm   = w & 1;
    const int wn   = w >> 1;
    const int row0 = (int)bys * 128;
    const int col0 = (int)bxs * 128;

    const ushort_t* Ab0 = A0 + (long)bz * sA;
    const ushort_t* Ab1 = A1 + (long)bz * sA;
    const ushort_t* Bb  = B  + (long)bz * sB;

    const int sRow = w * 32 + (lane >> 2);
    // swizzled source k-chunk: (lane&3) ^ ((row_local>>1)&3), row_local = lane>>2
    const int sOff = (((lane & 3) ^ ((lane >> 3) & 3)) * 8);
    ushort_t* ldsA0 = &As[w * 1024];
    ushort_t* ldsA1 = &As[w * 1024 + 512];
    ushort_t* ldsB0 = &Bs[w * 1024];
    ushort_t* ldsB1 = &Bs[w * 1024 + 512];

    const int lr = lane & 15, q = lane >> 4;
    // fragment read at swizzled chunk position q ^ ((lr>>1)&3)
    const int aBase = (wm * 64 + lr) * 32 + (q ^ ((lr >> 1) & 3)) * 8;
    const int bBase = (wn * 64 + lr) * 32 + (q ^ ((lr >> 1) & 3)) * 8;

    f32x4 acc[4][4] = {};

    for (int k0 = 0; k0 < K; k0 += 32) {
        const ushort_t* Ap; int kk, ldaP;
        if (k0 < Ksplit) { Ap = Ab0; kk = k0;          ldaP = lda0; }
        else             { Ap = Ab1; kk = k0 - Ksplit; ldaP = lda1; }

        gld_lds16(Ap + (size_t)(row0 + sRow) * ldaP + kk + sOff, ldsA0);
        gld_lds16(Ap + (size_t)(row0 + sRow + 16) * ldaP + kk + sOff, ldsA1);
        gld_lds16(Bb + (size_t)(col0 + sRow) * ldb + k0 + sOff, ldsB0);
        gld_lds16(Bb + (size_t)(col0 + sRow + 16) * ldb + k0 + sOff, ldsB1);

        __syncthreads();

        bf16x8 af[4], bf[4];
        #pragma unroll
        for (int i = 0; i < 4; ++i)
            af[i] = *reinterpret_cast<const bf16x8*>(&As[aBase + i * 16 * 32]);
        #pragma unroll
        for (int j = 0; j < 4; ++j)
            bf[j] = *reinterpret_cast<const bf16x8*>(&Bs[bBase + j * 16 * 32]);
        #pragma unroll
        for (int i = 0; i < 4; ++i)
            #pragma unroll
            for (int j = 0; j < 4; ++j)
                acc[i][j] = __builtin_amdgcn_mfma_f32_16x16x32_bf16(af[i], bf[j], acc[i][j], 0, 0, 0);

        __syncthreads();
    }

    float biasv[4];
    int mj[4];
    #pragma unroll
    for (int j = 0; j < 4; ++j) {
        const int c = col0 + wn * 64 + j * 16 + lr;
        if (BIAS) biasv[j] = bias[c];
        if (PM)   mj[j] = rm2[(long)bz * N + c];
    }
    float* Cf = (float*)C + (long)bz * sC;
    ushort_t* Ch = (ushort_t*)C + (long)bz * sC;

    #pragma unroll
    for (int i = 0; i < 4; ++i) {
        const int rg0 = row0 + wm * 64 + i * 16 + q * 4;   // first of 4 consecutive rows
        int mi4[4];
        if (RM || PM) {
            #pragma unroll
            for (int r = 0; r < 4; ++r) {
                const int row = rg0 + r;
                if (PM)      mi4[r] = rm1[(long)bz * M + row];
                else         mi4[r] = (row < Mhalf) ? rm1[row] : rm2[row - Mhalf];
            }
        }
        #pragma unroll
        for (int j = 0; j < 4; ++j) {
            const int c = col0 + wn * 64 + j * 16 + lr;
            ushort_t tp[4];
            #pragma unroll
            for (int r = 0; r < 4; ++r) {
                const int row = rg0 + r;
                float v = acc[i][j][r];
                if (BIAS) v += biasv[j];
                if (LRELU) v = lrelu_f(v);
                if (RM) v *= (float)mi4[r];
                if (PM) { if (!(mi4[r] && mj[j])) v += NEG_BIG; }
                const size_t a = (size_t)row * ldc + c;
                if (BF16OUT) Ch[a] = f2bf(v); else Cf[a] = v;
                if (TWOUT) tp[r] = f2bf(v);
            }
            if (TWOUT) {
                // slot-swapped: r1 batches -> slots 64..127, r2 batches -> 0..63
                const size_t ta = ((size_t)(((rg0 >> 9) + 64) & 127)) * 262144
                                + (size_t)c * 512 + (rg0 & 511);
                *reinterpret_cast<uint2*>(CT + ta) = *reinterpret_cast<uint2*>(tp);
            }
        }
    }
}

// ---------------------------------------------------------------------------
// fp32 -> bf16 convert for both inputs (y selects tensor)
__global__ __launch_bounds__(256)
void cvt2_f32_bf16(const float* __restrict__ a, const float* __restrict__ b,
                   ushort_t* __restrict__ oa, ushort_t* __restrict__ ob)
{
    const float* in = blockIdx.y ? b : a;
    ushort_t* out = blockIdx.y ? ob : oa;
    const long i = ((long)blockIdx.x * 256 + threadIdx.x) * 4;
    const float4 v = *reinterpret_cast<const float4*>(in + i);
    ushort_t o[4] = { f2bf(v.x), f2bf(v.y), f2bf(v.z), f2bf(v.w) };
    *reinterpret_cast<uint2*>(out + i) = *reinterpret_cast<uint2*>(o);
}

// all 4 weight transposes in one launch: fp32 [R,C] -> bf16 [C,R], z selects
__global__ __launch_bounds__(256)
void transpose_cvt4(const float* __restrict__ W1, const float* __restrict__ W2,
                    const float* __restrict__ Wc1, const float* __restrict__ Wc2,
                    ushort_t* __restrict__ W1t, ushort_t* __restrict__ W2t,
                    ushort_t* __restrict__ Wc1t, ushort_t* __restrict__ Wc2t)
{
    __shared__ float t[32][33];
    const int z = blockIdx.z;
    const float* in = (z == 0) ? W1 : (z == 1) ? W2 : (z == 2) ? Wc1 : Wc2;
    ushort_t* out   = (z == 0) ? W1t : (z == 1) ? W2t : (z == 2) ? Wc1t : Wc2t;
    const int R = (z == 2) ? 1024 : 512;
    const int C = 512;
    const int c0 = blockIdx.x * 32, r0 = blockIdx.y * 32;
    if (r0 >= R) return;
    const int tx = threadIdx.x & 31, ty = threadIdx.x >> 5;
    #pragma unroll
    for (int p = 0; p < 4; ++p)
        t[ty + p * 8][tx] = in[(size_t)(r0 + ty + p * 8) * C + c0 + tx];
    __syncthreads();
    #pragma unroll
    for (int p = 0; p < 4; ++p)
        out[(size_t)(c0 + ty + p * 8) * R + r0 + tx] = f2bf(t[tx][ty + p * 8]);
}

// one wave per row: max + 1/sum(exp)
__global__ __launch_bounds__(256)
void row_stats(const float* __restrict__ o, float* __restrict__ rmax,
               float* __restrict__ rsinv, int L)
{
    const int row  = blockIdx.x * 4 + (threadIdx.x >> 6);
    const int lane = threadIdx.x & 63;
    const float* p = o + (long)row * L;
    float m = -3.0e38f;
    for (int j = lane; j < L; j += 64) m = fmaxf(m, p[j]);
    #pragma unroll
    for (int off = 32; off > 0; off >>= 1) m = fmaxf(m, __shfl_xor(m, off));
    float s = 0.0f;
    for (int j = lane; j < L; j += 64) s += __expf(p[j] - m);
    #pragma unroll
    for (int off = 32; off > 0; off >>= 1) s += __shfl_xor(s, off);
    if (lane == 0) { rmax[row] = m; rsinv[row] = 1.0f / s; }
}

// column stats phase 1: each block scans 64 rows for 256 columns (split-K)
__global__ __launch_bounds__(256)
void col_part(const float* __restrict__ o, float* __restrict__ pm,
              float* __restrict__ ps, int L)
{
    const int b  = blockIdx.z;
    const int rc = blockIdx.y;
    const int j  = blockIdx.x * 256 + threadIdx.x;
    const float* p = o + (long)b * L * L + (long)rc * 64 * L + j;
    float m = -3.0e38f, s = 0.0f;
    #pragma unroll 4
    for (int i = 0; i < 64; ++i) {
        const float x = p[(long)i * L];
        const float mn = fmaxf(m, x);
        s = s * __expf(m - mn) + __expf(x - mn);
        m = mn;
    }
    const long idx = ((long)b * 8 + rc) * L + j;
    pm[idx] = m;
    ps[idx] = s;
}

// column stats phase 2: merge 8 partials per column
__global__ __launch_bounds__(256)
void col_combine(const float* __restrict__ pm, const float* __restrict__ ps,
                 float* __restrict__ cmax, float* __restrict__ csinv, int L)
{
    const int b = blockIdx.y;
    const int j = blockIdx.x * 256 + threadIdx.x;
    float mk[8], sk[8];
    #pragma unroll
    for (int k = 0; k < 8; ++k) {
        mk[k] = pm[((long)b * 8 + k) * L + j];
        sk[k] = ps[((long)b * 8 + k) * L + j];
    }
    float m = -3.0e38f;
    #pragma unroll
    for (int k = 0; k < 8; ++k) m = fmaxf(m, mk[k]);
    float s = 0.0f;
    #pragma unroll
    for (int k = 0; k < 8; ++k) s += sk[k] * __expf(mk[k] - m);
    cmax[b * L + j]  = m;
    csinv[b * L + j] = 1.0f / s;
}

// tiled: o1[b,i,j] = rowsm * mpos (bf16), o2T[b,j,i] = colsm * mpos (bf16)
__global__ __launch_bounds__(256)
void softmax_apply(const float* __restrict__ o,
                   ushort_t* __restrict__ o1, ushort_t* __restrict__ o2T,
                   const float* __restrict__ rmax, const float* __restrict__ rsinv,
                   const float* __restrict__ cmax, const float* __restrict__ csinv,
                   const int* __restrict__ m1, const int* __restrict__ m2)
{
    __shared__ ushort_t t[32][33];
    const int b = blockIdx.z;
    const long bo = (long)b * 512 * 512;
    const int j0 = blockIdx.x * 32, i0 = blockIdx.y * 32;
    const int tx = threadIdx.x & 31, ty = threadIdx.x >> 5;
    const int col = b * 512 + j0 + tx;
    const int mjv = m2[col];
    const float cm = cmax[col], cs = csinv[col];
    #pragma unroll
    for (int p = 0; p < 4; ++p) {
        const int i = i0 + ty + p * 8;
        const int row = b * 512 + i;
        const float x = o[bo + (long)i * 512 + j0 + tx];
        const float mp = (m1[row] != 0 && mjv != 0) ? 1.0f : 0.0f;
        o1[bo + (long)i * 512 + j0 + tx] = f2bf(__expf(x - rmax[row]) * rsinv[row] * mp);
        t[ty + p * 8][tx] = f2bf(__expf(x - cm) * cs * mp);
    }
    __syncthreads();
    #pragma unroll
    for (int p = 0; p < 4; ++p)
        o2T[bo + (long)(j0 + ty + p * 8) * 512 + i0 + tx] = t[tx][ty + p * 8];
}

// ---------------------------------------------------------------------------
extern "C" void kernel_launch(void* const* d_in, const int* in_sizes, int n_in,
                              void* d_out, int out_size, void* d_ws, size_t ws_size,
                              hipStream_t stream)
{
    const float* r1  = (const float*)d_in[0];
    const float* r2  = (const float*)d_in[1];
    const int*   m1  = (const int*)d_in[2];
    const int*   m2  = (const int*)d_in[3];
    const float* W1  = (const float*)d_in[4];
    const float* b1v = (const float*)d_in[5];
    const float* W2  = (const float*)d_in[6];
    const float* b2v = (const float*)d_in[7];
    const float* Wc1 = (const float*)d_in[8];
    const float* bc1 = (const float*)d_in[9];
    const float* Wc2 = (const float*)d_in[10];
    const float* bc2 = (const float*)d_in[11];
    float* out = (float*)d_out;

    constexpr int  Bn = 64, L = 512, D = 512;
    constexpr long CE = (long)Bn * L * D;  // 16,777,216 elements
    constexpr long S  = (long)L * L;       // 262,144
    constexpr int  NR = Bn * L;            // 32,768

    // d_out: 4 bf16 scratch slots (all dead before final fp32 writes)
    ushort_t* O    = (ushort_t*)d_out;
    ushort_t* r1b  = O;            // slot0: r1 bf16 (dead after GEMM 1)
    ushort_t* r2b  = O + CE;       // slot1: r2 bf16
    // After GEMM 2 (TWOUT slot-swapped): [slot0 | slot1] = [r2mT | r1mT],
    // uniform batch stride S from base O for the merged ctx GEMM.
    ushort_t* TT   = O;
    ushort_t* o1b  = O + 2 * CE;   // slot2: o1  (batches 0..63)
    // slot3 = o1b + CE = o2T (batches 64..127 of the same strided array)
    ushort_t* o2Tb = O + 3 * CE;

    // workspace
    char* wsb = (char*)d_ws;
    // R0 [0,4CE): h (2CE ushorts) -> obuf (CE floats) -> r1c‖r2c (2CE ushorts)
    ushort_t* hb   = (ushort_t*)wsb;
    float*    obuf = (float*)wsb;
    ushort_t* r1c  = (ushort_t*)wsb;
    // R1 [4CE,8CE): hc (compare hidden)
    ushort_t* hc   = (ushort_t*)(wsb + 4 * CE);
    // R2 [8CE,12CE): r1m ‖ r2m
    ushort_t* r1mb = (ushort_t*)(wsb + 8 * CE);
    ushort_t* r2mb = (ushort_t*)(wsb + 10 * CE);
    // R3 [12CE, ...): weights + stats
    ushort_t* W1t  = (ushort_t*)(wsb + 12 * CE);
    ushort_t* W2t  = W1t + 512 * 512;
    ushort_t* Wc1t = W2t + 512 * 512;            // [512,1024]
    ushort_t* Wc2t = Wc1t + 512 * 1024;
    float* rmaxv = (float*)(Wc2t + 512 * 512);
    float* rsinv = rmaxv + NR;
    float* cmaxv = rsinv + NR;
    float* csinv = cmaxv + NR;
    float* pmbuf = csinv + NR;                   // 8*512*64 floats
    float* psbuf = pmbuf + 8 * L * Bn;

    const dim3 blk(256);
    const dim3 gD2(D / 128, 2 * NR / 128, 1);    // combined dense: 4 x 512
    const dim3 gB(L / 128, L / 128, Bn);         // batched score: 4 x 4 x 64
    const dim3 gB2(L / 128, L / 128, 2 * Bn);    // merged ctx: 4 x 4 x 128

    // 0) convert inputs + weights
    cvt2_f32_bf16<<<dim3(CE / 1024, 2), blk, 0, stream>>>(r1, r2, r1b, r2b);
    transpose_cvt4<<<dim3(16, 32, 4), blk, 0, stream>>>(
        W1, W2, Wc1, Wc2, W1t, W2t, Wc1t, Wc2t);

    // 1) h = lrelu([r1;r2] @ W1 + b1)   M=65536
    gemm_nt<true,true,false,false,true,false><<<gD2, blk, 0, stream>>>(
        r1b, r1b, D, D, D, W1t, D, b1v, nullptr, nullptr, hb, D,
        nullptr, 0, 2 * NR, D, D, 0, 0, 0);
    // 2) [r1m;r2m] = lrelu(h @ W2 + b2) * mask  + fused transposed copies
    gemm_nt<true,true,true,false,true,true><<<gD2, blk, 0, stream>>>(
        hb, hb, D, D, D, W2t, D, b2v, m1, m2, r1mb, D,
        TT, NR, 2 * NR, D, D, 0, 0, 0);
    // 3) o = r1m @ r2m^T + pairmask  (batched fp32)
    gemm_nt<false,false,false,true,false,false><<<gB, blk, 0, stream>>>(
        r1mb, r1mb, D, D, D, r2mb, D, nullptr, m1, m2, obuf, L,
        nullptr, 0, L, L, D, S, S, S);
    // 4) softmax stats
    row_stats<<<dim3(NR / 4), blk, 0, stream>>>(obuf, rmaxv, rsinv, L);
    col_part<<<dim3(L / 256, 8, Bn), blk, 0, stream>>>(obuf, pmbuf, psbuf, L);
    col_combine<<<dim3(L / 256, Bn), blk, 0, stream>>>(pmbuf, psbuf, cmaxv, csinv, L);
    // 5) o1 (bf16) + o2^T (bf16)
    softmax_apply<<<dim3(16, 16, Bn), blk, 0, stream>>>(
        obuf, o1b, o2Tb, rmaxv, rsinv, cmaxv, csinv, m1, m2);
    // 6+7 merged) z<64: r1_c = o1 @ r2m^T-slots ; z>=64: r2_c = o2T @ r1m^T-slots
    gemm_nt<false,false,false,false,true,false><<<gB2, blk, 0, stream>>>(
        o1b, o1b, L, L, L, TT, L, nullptr, nullptr, nullptr, r1c, D,
        nullptr, 0, L, D, L, S, S, S);
    // 8) hc = lrelu(cat([r1m;r2m],[r1c;r2c]) @ Wc1 + bc1)  M=65536, K=1024
    gemm_nt<true,true,false,false,true,false><<<gD2, blk, 0, stream>>>(
        r1mb, r1c, D, D, D, Wc1t, 2 * D, bc1, nullptr, nullptr, hc, D,
        nullptr, 0, 2 * NR, D, 2 * D, 0, 0, 0);
    // 9) [out1;out2] = lrelu(hc @ Wc2 + bc2) * mask  (fp32, full d_out)
    gemm_nt<true,true,true,false,false,false><<<gD2, blk, 0, stream>>>(
        hc, hc, D, D, D, Wc2t, D, bc2, m1, m2, out, D,
        nullptr, NR, 2 * NR, D, D, 0, 0, 0);
}

// Round 2
// 674.829 us; speedup vs baseline: 1.0797x; 1.0147x over previous
//
#include <hip/hip_runtime.h>

#define LRELU_SLOPE 0.01f
#define NEG_BIG -1e10f

typedef unsigned short ushort_t;
typedef __bf16 bf16x8 __attribute__((ext_vector_type(8)));
typedef float f32x4 __attribute__((ext_vector_type(4)));

static __device__ __forceinline__ float lrelu_f(float x) {
    return x >= 0.0f ? x : LRELU_SLOPE * x;
}

static __device__ __forceinline__ ushort_t f2bf(float f) {
    unsigned int u = __float_as_uint(f);
    u += 0x7fffu + ((u >> 16) & 1u);
    return (ushort_t)(u >> 16);
}

static __device__ __forceinline__ void gld_lds16(const ushort_t* g, ushort_t* l) {
    __builtin_amdgcn_global_load_lds((const __attribute__((address_space(1))) void*)g,
                                     (__attribute__((address_space(3))) void*)l,
                                     16, 0, 0);
}

// ---------------------------------------------------------------------------
// NT bf16 MFMA GEMM: C[m,n] = epi( sum_k A[m,k] * B[n,k] )
// 128x128 tile, 4 waves (2x2), BK=32, 16x16x32 MFMA.
// Software pipeline (T3-minimum 2-phase): LDS double-buffered; tile t+1's
// global_load_lds issued BEFORE computing tile t; counted s_waitcnt vmcnt(4)
// (waits only tile-t's 4 loads, leaves t+1's 4 in flight across the raw
// s_barrier). __syncthreads() is NOT used in the K-loop — it would force a
// full vmcnt(0) drain per step, which was the dominant stall (R1: 14.7% HBM,
// 23% MfmaUtil, both pipes idle => latency-bound on the per-step drain).
// Explicit lgkmcnt(0) before the trailing barrier pins ds_read completion
// so the next stage can't overwrite a buffer another wave still reads.
// LDS layout XOR-swizzled: row r's k-chunk c (16B) stored at position
// c ^ ((r>>1)&3)  -> ds_read_b128 fragment reads are bank-conflict-free.
// XCD-aware tile remap (R0, kept): lin -> (lin%8)*(nwg/8)+lin/8 so each XCD
// owns a contiguous tile range; A panels fetched once (FETCH 265->78 MB).
// RM mask: row < Mhalf ? rm1[row] : rm2[row-Mhalf]  (combined-M launches)
// PM mask: rm1[bz*M+row] && rm2[bz*N+col] else += NEG_BIG (batched score GEMM)
// TWOUT: also store bf16 transposed per-batch with slot swap:
//   CT[(((row>>9)+64)&127)*S + col*512 + (row&511)]  -> [r2mT | r1mT] order
// ---------------------------------------------------------------------------
template<bool BIAS, bool LRELU, bool RM, bool PM, bool BF16OUT, bool TWOUT>
__global__ __launch_bounds__(256)
void gemm_nt(const ushort_t* __restrict__ A0, const ushort_t* __restrict__ A1,
             int Ksplit, int lda0, int lda1,
             const ushort_t* __restrict__ B, int ldb,
             const float* __restrict__ bias,
             const int* __restrict__ rm1, const int* __restrict__ rm2,
             void* __restrict__ C, int ldc,
             ushort_t* __restrict__ CT, int Mhalf,
             int M, int N, int K,
             long sA, long sB, long sC)
{
    __shared__ ushort_t As[2][128 * 32];
    __shared__ ushort_t Bs[2][128 * 32];

    // XCD-aware block remap (see header comment)
    const unsigned nbx = gridDim.x, nby = gridDim.y;
    unsigned lin = blockIdx.x + nbx * (blockIdx.y + nby * blockIdx.z);
    const unsigned nwg = nbx * nby * gridDim.z;
    if ((nwg & 7u) == 0u)
        lin = (lin & 7u) * (nwg >> 3) + (lin >> 3);
    const unsigned bxs = lin % nbx;
    const unsigned t1  = lin / nbx;
    const unsigned bys = t1 % nby;
    const unsigned bzs = t1 / nby;

    const int bz   = (int)bzs;
    const int tid  = threadIdx.x;
    const int w    = tid >> 6;
    const int lane = tid & 63;
    const int wm   = w & 1;
    const int wn   = w >> 1;
    const int row0 = (int)bys * 128;
    const int col0 = (int)bxs * 128;

    const ushort_t* Ab0 = A0 + (long)bz * sA;
    const ushort_t* Ab1 = A1 + (long)bz * sA;
    const ushort_t* Bb  = B  + (long)bz * sB;

    const int sRow = w * 32 + (lane >> 2);
    // swizzled source k-chunk: (lane&3) ^ ((row_local>>1)&3), row_local = lane>>2
    const int sOff = (((lane & 3) ^ ((lane >> 3) & 3)) * 8);

    const int lr = lane & 15, q = lane >> 4;
    // fragment read at swizzled chunk position q ^ ((lr>>1)&3)
    const int aBase = (wm * 64 + lr) * 32 + (q ^ ((lr >> 1) & 3)) * 8;
    const int bBase = (wn * 64 + lr) * 32 + (q ^ ((lr >> 1) & 3)) * 8;

    f32x4 acc[4][4] = {};

    // stage one BK=32 K-slice of A and B into LDS buffer (Ad, Bd)
    auto stage = [&](int k0g, ushort_t* Ad, ushort_t* Bd) {
        const ushort_t* Ap; int kk, ldaP;
        if (k0g < Ksplit) { Ap = Ab0; kk = k0g;          ldaP = lda0; }
        else              { Ap = Ab1; kk = k0g - Ksplit; ldaP = lda1; }
        gld_lds16(Ap + (size_t)(row0 + sRow) * ldaP + kk + sOff, Ad + w * 1024);
        gld_lds16(Ap + (size_t)(row0 + sRow + 16) * ldaP + kk + sOff, Ad + w * 1024 + 512);
        gld_lds16(Bb + (size_t)(col0 + sRow) * ldb + k0g + sOff, Bd + w * 1024);
        gld_lds16(Bb + (size_t)(col0 + sRow + 16) * ldb + k0g + sOff, Bd + w * 1024 + 512);
    };

    const int NT = K >> 5;
    stage(0, As[0], Bs[0]);

    for (int t = 0; t < NT; ++t) {
        ushort_t* Ac = As[t & 1];
        ushort_t* Bc = Bs[t & 1];

        if (t + 1 < NT) {
            stage((t + 1) << 5, As[(t + 1) & 1], Bs[(t + 1) & 1]);
            // tile t's 4 loads done; tile t+1's 4 stay in flight across barrier
            asm volatile("s_waitcnt vmcnt(4)" ::: "memory");
        } else {
            asm volatile("s_waitcnt vmcnt(0)" ::: "memory");
        }
        __builtin_amdgcn_s_barrier();

        bf16x8 af[4], bf[4];
        #pragma unroll
        for (int i = 0; i < 4; ++i)
            af[i] = *reinterpret_cast<const bf16x8*>(&Ac[aBase + i * 16 * 32]);
        #pragma unroll
        for (int j = 0; j < 4; ++j)
            bf[j] = *reinterpret_cast<const bf16x8*>(&Bc[bBase + j * 16 * 32]);
        #pragma unroll
        for (int i = 0; i < 4; ++i)
            #pragma unroll
            for (int j = 0; j < 4; ++j)
                acc[i][j] = __builtin_amdgcn_mfma_f32_16x16x32_bf16(af[i], bf[j], acc[i][j], 0, 0, 0);

        if (t + 1 < NT) {
            // all my ds_reads landed in regs before I let others overwrite buf
            asm volatile("s_waitcnt lgkmcnt(0)" ::: "memory");
            __builtin_amdgcn_s_barrier();
        }
    }

    float biasv[4];
    int mj[4];
    #pragma unroll
    for (int j = 0; j < 4; ++j) {
        const int c = col0 + wn * 64 + j * 16 + lr;
        if (BIAS) biasv[j] = bias[c];
        if (PM)   mj[j] = rm2[(long)bz * N + c];
    }
    float* Cf = (float*)C + (long)bz * sC;
    ushort_t* Ch = (ushort_t*)C + (long)bz * sC;

    #pragma unroll
    for (int i = 0; i < 4; ++i) {
        const int rg0 = row0 + wm * 64 + i * 16 + q * 4;   // first of 4 consecutive rows
        int mi4[4];
        if (RM || PM) {
            #pragma unroll
            for (int r = 0; r < 4; ++r) {
                const int row = rg0 + r;
                if (PM)      mi4[r] = rm1[(long)bz * M + row];
                else         mi4[r] = (row < Mhalf) ? rm1[row] : rm2[row - Mhalf];
            }
        }
        #pragma unroll
        for (int j = 0; j < 4; ++j) {
            const int c = col0 + wn * 64 + j * 16 + lr;
            ushort_t tp[4];
            #pragma unroll
            for (int r = 0; r < 4; ++r) {
                const int row = rg0 + r;
                float v = acc[i][j][r];
                if (BIAS) v += biasv[j];
                if (LRELU) v = lrelu_f(v);
                if (RM) v *= (float)mi4[r];
                if (PM) { if (!(mi4[r] && mj[j])) v += NEG_BIG; }
                const size_t a = (size_t)row * ldc + c;
                if (BF16OUT) Ch[a] = f2bf(v); else Cf[a] = v;
                if (TWOUT) tp[r] = f2bf(v);
            }
            if (TWOUT) {
                // slot-swapped: r1 batches -> slots 64..127, r2 batches -> 0..63
                const size_t ta = ((size_t)(((rg0 >> 9) + 64) & 127)) * 262144
                                + (size_t)c * 512 + (rg0 & 511);
                *reinterpret_cast<uint2*>(CT + ta) = *reinterpret_cast<uint2*>(tp);
            }
        }
    }
}

// ---------------------------------------------------------------------------
// fp32 -> bf16 convert for both inputs (y selects tensor)
__global__ __launch_bounds__(256)
void cvt2_f32_bf16(const float* __restrict__ a, const float* __restrict__ b,
                   ushort_t* __restrict__ oa, ushort_t* __restrict__ ob)
{
    const float* in = blockIdx.y ? b : a;
    ushort_t* out = blockIdx.y ? ob : oa;
    const long i = ((long)blockIdx.x * 256 + threadIdx.x) * 4;
    const float4 v = *reinterpret_cast<const float4*>(in + i);
    ushort_t o[4] = { f2bf(v.x), f2bf(v.y), f2bf(v.z), f2bf(v.w) };
    *reinterpret_cast<uint2*>(out + i) = *reinterpret_cast<uint2*>(o);
}

// all 4 weight transposes in one launch: fp32 [R,C] -> bf16 [C,R], z selects
__global__ __launch_bounds__(256)
void transpose_cvt4(const float* __restrict__ W1, const float* __restrict__ W2,
                    const float* __restrict__ Wc1, const float* __restrict__ Wc2,
                    ushort_t* __restrict__ W1t, ushort_t* __restrict__ W2t,
                    ushort_t* __restrict__ Wc1t, ushort_t* __restrict__ Wc2t)
{
    __shared__ float t[32][33];
    const int z = blockIdx.z;
    const float* in = (z == 0) ? W1 : (z == 1) ? W2 : (z == 2) ? Wc1 : Wc2;
    ushort_t* out   = (z == 0) ? W1t : (z == 1) ? W2t : (z == 2) ? Wc1t : Wc2t;
    const int R = (z == 2) ? 1024 : 512;
    const int C = 512;
    const int c0 = blockIdx.x * 32, r0 = blockIdx.y * 32;
    if (r0 >= R) return;
    const int tx = threadIdx.x & 31, ty = threadIdx.x >> 5;
    #pragma unroll
    for (int p = 0; p < 4; ++p)
        t[ty + p * 8][tx] = in[(size_t)(r0 + ty + p * 8) * C + c0 + tx];
    __syncthreads();
    #pragma unroll
    for (int p = 0; p < 4; ++p)
        out[(size_t)(c0 + ty + p * 8) * R + r0 + tx] = f2bf(t[tx][ty + p * 8]);
}

// one wave per row: max + 1/sum(exp)
__global__ __launch_bounds__(256)
void row_stats(const float* __restrict__ o, float* __restrict__ rmax,
               float* __restrict__ rsinv, int L)
{
    const int row  = blockIdx.x * 4 + (threadIdx.x >> 6);
    const int lane = threadIdx.x & 63;
    const float* p = o + (long)row * L;
    float m = -3.0e38f;
    for (int j = lane; j < L; j += 64) m = fmaxf(m, p[j]);
    #pragma unroll
    for (int off = 32; off > 0; off >>= 1) m = fmaxf(m, __shfl_xor(m, off));
    float s = 0.0f;
    for (int j = lane; j < L; j += 64) s += __expf(p[j] - m);
    #pragma unroll
    for (int off = 32; off > 0; off >>= 1) s += __shfl_xor(s, off);
    if (lane == 0) { rmax[row] = m; rsinv[row] = 1.0f / s; }
}

// column stats phase 1: each block scans 64 rows for 256 columns (split-K)
__global__ __launch_bounds__(256)
void col_part(const float* __restrict__ o, float* __restrict__ pm,
              float* __restrict__ ps, int L)
{
    const int b  = blockIdx.z;
    const int rc = blockIdx.y;
    const int j  = blockIdx.x * 256 + threadIdx.x;
    const float* p = o + (long)b * L * L + (long)rc * 64 * L + j;
    float m = -3.0e38f, s = 0.0f;
    #pragma unroll 4
    for (int i = 0; i < 64; ++i) {
        const float x = p[(long)i * L];
        const float mn = fmaxf(m, x);
        s = s * __expf(m - mn) + __expf(x - mn);
        m = mn;
    }
    const long idx = ((long)b * 8 + rc) * L + j;
    pm[idx] = m;
    ps[idx] = s;
}

// column stats phase 2: merge 8 partials per column
__global__ __launch_bounds__(256)
void col_combine(const float* __restrict__ pm, const float* __restrict__ ps,
                 float* __restrict__ cmax, float* __restrict__ csinv, int L)
{
    const int b = blockIdx.y;
    const int j = blockIdx.x * 256 + threadIdx.x;
    float mk[8], sk[8];
    #pragma unroll
    for (int k = 0; k < 8; ++k) {
        mk[k] = pm[((long)b * 8 + k) * L + j];
        sk[k] = ps[((long)b * 8 + k) * L + j];
    }
    float m = -3.0e38f;
    #pragma unroll
    for (int k = 0; k < 8; ++k) m = fmaxf(m, mk[k]);
    float s = 0.0f;
    #pragma unroll
    for (int k = 0; k < 8; ++k) s += sk[k] * __expf(mk[k] - m);
    cmax[b * L + j]  = m;
    csinv[b * L + j] = 1.0f / s;
}

// tiled: o1[b,i,j] = rowsm * mpos (bf16), o2T[b,j,i] = colsm * mpos (bf16)
__global__ __launch_bounds__(256)
void softmax_apply(const float* __restrict__ o,
                   ushort_t* __restrict__ o1, ushort_t* __restrict__ o2T,
                   const float* __restrict__ rmax, const float* __restrict__ rsinv,
                   const float* __restrict__ cmax, const float* __restrict__ csinv,
                   const int* __restrict__ m1, const int* __restrict__ m2)
{
    __shared__ ushort_t t[32][33];
    const int b = blockIdx.z;
    const long bo = (long)b * 512 * 512;
    const int j0 = blockIdx.x * 32, i0 = blockIdx.y * 32;
    const int tx = threadIdx.x & 31, ty = threadIdx.x >> 5;
    const int col = b * 512 + j0 + tx;
    const int mjv = m2[col];
    const float cm = cmax[col], cs = csinv[col];
    #pragma unroll
    for (int p = 0; p < 4; ++p) {
        const int i = i0 + ty + p * 8;
        const int row = b * 512 + i;
        const float x = o[bo + (long)i * 512 + j0 + tx];
        const float mp = (m1[row] != 0 && mjv != 0) ? 1.0f : 0.0f;
        o1[bo + (long)i * 512 + j0 + tx] = f2bf(__expf(x - rmax[row]) * rsinv[row] * mp);
        t[ty + p * 8][tx] = f2bf(__expf(x - cm) * cs * mp);
    }
    __syncthreads();
    #pragma unroll
    for (int p = 0; p < 4; ++p)
        o2T[bo + (long)(j0 + ty + p * 8) * 512 + i0 + tx] = t[tx][ty + p * 8];
}

// ---------------------------------------------------------------------------
extern "C" void kernel_launch(void* const* d_in, const int* in_sizes, int n_in,
                              void* d_out, int out_size, void* d_ws, size_t ws_size,
                              hipStream_t stream)
{
    const float* r1  = (const float*)d_in[0];
    const float* r2  = (const float*)d_in[1];
    const int*   m1  = (const int*)d_in[2];
    const int*   m2  = (const int*)d_in[3];
    const float* W1  = (const float*)d_in[4];
    const float* b1v = (const float*)d_in[5];
    const float* W2  = (const float*)d_in[6];
    const float* b2v = (const float*)d_in[7];
    const float* Wc1 = (const float*)d_in[8];
    const float* bc1 = (const float*)d_in[9];
    const float* Wc2 = (const float*)d_in[10];
    const float* bc2 = (const float*)d_in[11];
    float* out = (float*)d_out;

    constexpr int  Bn = 64, L = 512, D = 512;
    constexpr long CE = (long)Bn * L * D;  // 16,777,216 elements
    constexpr long S  = (long)L * L;       // 262,144
    constexpr int  NR = Bn * L;            // 32,768

    // d_out: 4 bf16 scratch slots (all dead before final fp32 writes)
    ushort_t* O    = (ushort_t*)d_out;
    ushort_t* r1b  = O;            // slot0: r1 bf16 (dead after GEMM 1)
    ushort_t* r2b  = O + CE;       // slot1: r2 bf16
    // After GEMM 2 (TWOUT slot-swapped): [slot0 | slot1] = [r2mT | r1mT],
    // uniform batch stride S from base O for the merged ctx GEMM.
    ushort_t* TT   = O;
    ushort_t* o1b  = O + 2 * CE;   // slot2: o1  (batches 0..63)
    // slot3 = o1b + CE = o2T (batches 64..127 of the same strided array)
    ushort_t* o2Tb = O + 3 * CE;

    // workspace
    char* wsb = (char*)d_ws;
    // R0 [0,4CE): h (2CE ushorts) -> obuf (CE floats) -> r1c‖r2c (2CE ushorts)
    ushort_t* hb   = (ushort_t*)wsb;
    float*    obuf = (float*)wsb;
    ushort_t* r1c  = (ushort_t*)wsb;
    // R1 [4CE,8CE): hc (compare hidden)
    ushort_t* hc   = (ushort_t*)(wsb + 4 * CE);
    // R2 [8CE,12CE): r1m ‖ r2m
    ushort_t* r1mb = (ushort_t*)(wsb + 8 * CE);
    ushort_t* r2mb = (ushort_t*)(wsb + 10 * CE);
    // R3 [12CE, ...): weights + stats
    ushort_t* W1t  = (ushort_t*)(wsb + 12 * CE);
    ushort_t* W2t  = W1t + 512 * 512;
    ushort_t* Wc1t = W2t + 512 * 512;            // [512,1024]
    ushort_t* Wc2t = Wc1t + 512 * 1024;
    float* rmaxv = (float*)(Wc2t + 512 * 512);
    float* rsinv = rmaxv + NR;
    float* cmaxv = rsinv + NR;
    float* csinv = cmaxv + NR;
    float* pmbuf = csinv + NR;                   // 8*512*64 floats
    float* psbuf = pmbuf + 8 * L * Bn;

    const dim3 blk(256);
    const dim3 gD2(D / 128, 2 * NR / 128, 1);    // combined dense: 4 x 512
    const dim3 gB(L / 128, L / 128, Bn);         // batched score: 4 x 4 x 64
    const dim3 gB2(L / 128, L / 128, 2 * Bn);    // merged ctx: 4 x 4 x 128

    // 0) convert inputs + weights
    cvt2_f32_bf16<<<dim3(CE / 1024, 2), blk, 0, stream>>>(r1, r2, r1b, r2b);
    transpose_cvt4<<<dim3(16, 32, 4), blk, 0, stream>>>(
        W1, W2, Wc1, Wc2, W1t, W2t, Wc1t, Wc2t);

    // 1) h = lrelu([r1;r2] @ W1 + b1)   M=65536
    gemm_nt<true,true,false,false,true,false><<<gD2, blk, 0, stream>>>(
        r1b, r1b, D, D, D, W1t, D, b1v, nullptr, nullptr, hb, D,
        nullptr, 0, 2 * NR, D, D, 0, 0, 0);
    // 2) [r1m;r2m] = lrelu(h @ W2 + b2) * mask  + fused transposed copies
    gemm_nt<true,true,true,false,true,true><<<gD2, blk, 0, stream>>>(
        hb, hb, D, D, D, W2t, D, b2v, m1, m2, r1mb, D,
        TT, NR, 2 * NR, D, D, 0, 0, 0);
    // 3) o = r1m @ r2m^T + pairmask  (batched fp32)
    gemm_nt<false,false,false,true,false,false><<<gB, blk, 0, stream>>>(
        r1mb, r1mb, D, D, D, r2mb, D, nullptr, m1, m2, obuf, L,
        nullptr, 0, L, L, D, S, S, S);
    // 4) softmax stats
    row_stats<<<dim3(NR / 4), blk, 0, stream>>>(obuf, rmaxv, rsinv, L);
    col_part<<<dim3(L / 256, 8, Bn), blk, 0, stream>>>(obuf, pmbuf, psbuf, L);
    col_combine<<<dim3(L / 256, Bn), blk, 0, stream>>>(pmbuf, psbuf, cmaxv, csinv, L);
    // 5) o1 (bf16) + o2^T (bf16)
    softmax_apply<<<dim3(16, 16, Bn), blk, 0, stream>>>(
        obuf, o1b, o2Tb, rmaxv, rsinv, cmaxv, csinv, m1, m2);
    // 6+7 merged) z<64: r1_c = o1 @ r2m^T-slots ; z>=64: r2_c = o2T @ r1m^T-slots
    gemm_nt<false,false,false,false,true,false><<<gB2, blk, 0, stream>>>(
        o1b, o1b, L, L, L, TT, L, nullptr, nullptr, nullptr, r1c, D,
        nullptr, 0, L, D, L, S, S, S);
    // 8) hc = lrelu(cat([r1m;r2m],[r1c;r2c]) @ Wc1 + bc1)  M=65536, K=1024
    gemm_nt<true,true,false,false,true,false><<<gD2, blk, 0, stream>>>(
        r1mb, r1c, D, D, D, Wc1t, 2 * D, bc1, nullptr, nullptr, hc, D,
        nullptr, 0, 2 * NR, D, 2 * D, 0, 0, 0);
    // 9) [out1;out2] = lrelu(hc @ Wc2 + bc2) * mask  (fp32, full d_out)
    gemm_nt<true,true,true,false,false,false><<<gD2, blk, 0, stream>>>(
        hc, hc, D, D, D, Wc2t, D, bc2, m1, m2, out, D,
        nullptr, NR, 2 * NR, D, D, 0, 0, 0);
}

// Round 3
// 661.920 us; speedup vs baseline: 1.1007x; 1.0195x over previous
//
#include <hip/hip_runtime.h>

#define LRELU_SLOPE 0.01f
#define NEG_BIG -1e10f

typedef unsigned short ushort_t;
typedef __bf16 bf16x8 __attribute__((ext_vector_type(8)));
typedef float f32x4 __attribute__((ext_vector_type(4)));

static __device__ __forceinline__ float lrelu_f(float x) {
    return x >= 0.0f ? x : LRELU_SLOPE * x;
}

static __device__ __forceinline__ ushort_t f2bf(float f) {
    unsigned int u = __float_as_uint(f);
    u += 0x7fffu + ((u >> 16) & 1u);
    return (ushort_t)(u >> 16);
}

static __device__ __forceinline__ void gld_lds16(const ushort_t* g, ushort_t* l) {
    __builtin_amdgcn_global_load_lds((const __attribute__((address_space(1))) void*)g,
                                     (__attribute__((address_space(3))) void*)l,
                                     16, 0, 0);
}

// ---------------------------------------------------------------------------
// NT bf16 MFMA GEMM: C[m,n] = epi( sum_k A[m,k] * B[n,k] )
// 128x128 tile, 4 waves (2x2), BK=32, 16x16x32 MFMA.
// Depth-2 software pipeline, 3 LDS buffers, ONE barrier per K-step:
//   iter t: vmcnt(4) [stage t landed, stage t+1 in flight] -> s_barrier ->
//           issue stage(t+2) into buf (t+2)%3 -> ds_read buf t%3 -> 16 MFMA.
// Rationale (R2 counters: MfmaUtil 26%, HBM 17%, both idle => latency-bound):
// depth-1 prefetch gave only 1 iter (~300cy) of cover vs ~900cy HBM latency.
// Depth-2 gives ~2 iters. Stage is issued AFTER the leading barrier so the
// buffer overwritten ((t+2)%3 == (t-1)%3) was provably consumed: every wave
// drained its iter-t-1 ds_reads into regs before reaching the iter-t barrier
// (MFMA issue requires lgkmcnt drain). This removes R1's trailing
// lgkmcnt(0)+s_barrier entirely (1 barrier/iter instead of 2).
// Memory-clobbered asm pins ds_reads after the barrier (no hoist).
// LDS layout XOR-swizzled: row r's k-chunk c (16B) stored at position
// c ^ ((r>>1)&3)  -> ds_read_b128 fragment reads are bank-conflict-free.
// XCD-aware tile remap (R0, kept): lin -> (lin%8)*(nwg/8)+lin/8 so each XCD
// owns a contiguous tile range; A panels fetched once (FETCH 265->78 MB).
// RM mask: row < Mhalf ? rm1[row] : rm2[row-Mhalf]  (combined-M launches)
// PM mask: rm1[bz*M+row] && rm2[bz*N+col] else += NEG_BIG (batched score GEMM)
// TWOUT: also store bf16 transposed per-batch with slot swap:
//   CT[(((row>>9)+64)&127)*S + col*512 + (row&511)]  -> [r2mT | r1mT] order
// ---------------------------------------------------------------------------
template<bool BIAS, bool LRELU, bool RM, bool PM, bool BF16OUT, bool TWOUT>
__global__ __launch_bounds__(256)
void gemm_nt(const ushort_t* __restrict__ A0, const ushort_t* __restrict__ A1,
             int Ksplit, int lda0, int lda1,
             const ushort_t* __restrict__ B, int ldb,
             const float* __restrict__ bias,
             const int* __restrict__ rm1, const int* __restrict__ rm2,
             void* __restrict__ C, int ldc,
             ushort_t* __restrict__ CT, int Mhalf,
             int M, int N, int K,
             long sA, long sB, long sC)
{
    __shared__ ushort_t As[3][128 * 32];
    __shared__ ushort_t Bs[3][128 * 32];

    // XCD-aware block remap (see header comment)
    const unsigned nbx = gridDim.x, nby = gridDim.y;
    unsigned lin = blockIdx.x + nbx * (blockIdx.y + nby * blockIdx.z);
    const unsigned nwg = nbx * nby * gridDim.z;
    if ((nwg & 7u) == 0u)
        lin = (lin & 7u) * (nwg >> 3) + (lin >> 3);
    const unsigned bxs = lin % nbx;
    const unsigned t1  = lin / nbx;
    const unsigned bys = t1 % nby;
    const unsigned bzs = t1 / nby;

    const int bz   = (int)bzs;
    const int tid  = threadIdx.x;
    const int w    = tid >> 6;
    const int lane = tid & 63;
    const int wm   = w & 1;
    const int wn   = w >> 1;
    const int row0 = (int)bys * 128;
    const int col0 = (int)bxs * 128;

    const ushort_t* Ab0 = A0 + (long)bz * sA;
    const ushort_t* Ab1 = A1 + (long)bz * sA;
    const ushort_t* Bb  = B  + (long)bz * sB;

    const int sRow = w * 32 + (lane >> 2);
    // swizzled source k-chunk: (lane&3) ^ ((row_local>>1)&3), row_local = lane>>2
    const int sOff = (((lane & 3) ^ ((lane >> 3) & 3)) * 8);

    const int lr = lane & 15, q = lane >> 4;
    // fragment read at swizzled chunk position q ^ ((lr>>1)&3)
    const int aBase = (wm * 64 + lr) * 32 + (q ^ ((lr >> 1) & 3)) * 8;
    const int bBase = (wn * 64 + lr) * 32 + (q ^ ((lr >> 1) & 3)) * 8;

    f32x4 acc[4][4] = {};

    // stage one BK=32 K-slice of A and B into LDS buffer (Ad, Bd)
    auto stage = [&](int k0g, ushort_t* Ad, ushort_t* Bd) {
        const ushort_t* Ap; int kk, ldaP;
        if (k0g < Ksplit) { Ap = Ab0; kk = k0g;          ldaP = lda0; }
        else              { Ap = Ab1; kk = k0g - Ksplit; ldaP = lda1; }
        gld_lds16(Ap + (size_t)(row0 + sRow) * ldaP + kk + sOff, Ad + w * 1024);
        gld_lds16(Ap + (size_t)(row0 + sRow + 16) * ldaP + kk + sOff, Ad + w * 1024 + 512);
        gld_lds16(Bb + (size_t)(col0 + sRow) * ldb + k0g + sOff, Bd + w * 1024);
        gld_lds16(Bb + (size_t)(col0 + sRow + 16) * ldb + k0g + sOff, Bd + w * 1024 + 512);
    };

    const int NT = K >> 5;
    stage(0, As[0], Bs[0]);
    if (NT > 1) stage(32, As[1], Bs[1]);

    for (int t = 0; t < NT; ++t) {
        // wait for stage t (leave stage t+1's 4 loads in flight)
        if (t + 1 < NT)
            asm volatile("s_waitcnt vmcnt(4)" ::: "memory");
        else
            asm volatile("s_waitcnt vmcnt(0)" ::: "memory");
        __builtin_amdgcn_s_barrier();
        asm volatile("" ::: "memory");   // pin ds_reads/stage after barrier

        if (t + 2 < NT) {
            const int nb = (t + 2) % 3;
            stage((t + 2) << 5, As[nb], Bs[nb]);
        }

        const ushort_t* Ac = As[t % 3];
        const ushort_t* Bc = Bs[t % 3];

        bf16x8 af[4], bf[4];
        #pragma unroll
        for (int i = 0; i < 4; ++i)
            af[i] = *reinterpret_cast<const bf16x8*>(&Ac[aBase + i * 16 * 32]);
        #pragma unroll
        for (int j = 0; j < 4; ++j)
            bf[j] = *reinterpret_cast<const bf16x8*>(&Bc[bBase + j * 16 * 32]);
        #pragma unroll
        for (int i = 0; i < 4; ++i)
            #pragma unroll
            for (int j = 0; j < 4; ++j)
                acc[i][j] = __builtin_amdgcn_mfma_f32_16x16x32_bf16(af[i], bf[j], acc[i][j], 0, 0, 0);
    }

    float biasv[4];
    int mj[4];
    #pragma unroll
    for (int j = 0; j < 4; ++j) {
        const int c = col0 + wn * 64 + j * 16 + lr;
        if (BIAS) biasv[j] = bias[c];
        if (PM)   mj[j] = rm2[(long)bz * N + c];
    }
    float* Cf = (float*)C + (long)bz * sC;
    ushort_t* Ch = (ushort_t*)C + (long)bz * sC;

    #pragma unroll
    for (int i = 0; i < 4; ++i) {
        const int rg0 = row0 + wm * 64 + i * 16 + q * 4;   // first of 4 consecutive rows
        int mi4[4];
        if (RM || PM) {
            #pragma unroll
            for (int r = 0; r < 4; ++r) {
                const int row = rg0 + r;
                if (PM)      mi4[r] = rm1[(long)bz * M + row];
                else         mi4[r] = (row < Mhalf) ? rm1[row] : rm2[row - Mhalf];
            }
        }
        #pragma unroll
        for (int j = 0; j < 4; ++j) {
            const int c = col0 + wn * 64 + j * 16 + lr;
            ushort_t tp[4];
            #pragma unroll
            for (int r = 0; r < 4; ++r) {
                const int row = rg0 + r;
                float v = acc[i][j][r];
                if (BIAS) v += biasv[j];
                if (LRELU) v = lrelu_f(v);
                if (RM) v *= (float)mi4[r];
                if (PM) { if (!(mi4[r] && mj[j])) v += NEG_BIG; }
                const size_t a = (size_t)row * ldc + c;
                if (BF16OUT) Ch[a] = f2bf(v); else Cf[a] = v;
                if (TWOUT) tp[r] = f2bf(v);
            }
            if (TWOUT) {
                // slot-swapped: r1 batches -> slots 64..127, r2 batches -> 0..63
                const size_t ta = ((size_t)(((rg0 >> 9) + 64) & 127)) * 262144
                                + (size_t)c * 512 + (rg0 & 511);
                *reinterpret_cast<uint2*>(CT + ta) = *reinterpret_cast<uint2*>(tp);
            }
        }
    }
}

// ---------------------------------------------------------------------------
// fp32 -> bf16 convert for both inputs (y selects tensor)
__global__ __launch_bounds__(256)
void cvt2_f32_bf16(const float* __restrict__ a, const float* __restrict__ b,
                   ushort_t* __restrict__ oa, ushort_t* __restrict__ ob)
{
    const float* in = blockIdx.y ? b : a;
    ushort_t* out = blockIdx.y ? ob : oa;
    const long i = ((long)blockIdx.x * 256 + threadIdx.x) * 4;
    const float4 v = *reinterpret_cast<const float4*>(in + i);
    ushort_t o[4] = { f2bf(v.x), f2bf(v.y), f2bf(v.z), f2bf(v.w) };
    *reinterpret_cast<uint2*>(out + i) = *reinterpret_cast<uint2*>(o);
}

// all 4 weight transposes in one launch: fp32 [R,C] -> bf16 [C,R], z selects
__global__ __launch_bounds__(256)
void transpose_cvt4(const float* __restrict__ W1, const float* __restrict__ W2,
                    const float* __restrict__ Wc1, const float* __restrict__ Wc2,
                    ushort_t* __restrict__ W1t, ushort_t* __restrict__ W2t,
                    ushort_t* __restrict__ Wc1t, ushort_t* __restrict__ Wc2t)
{
    __shared__ float t[32][33];
    const int z = blockIdx.z;
    const float* in = (z == 0) ? W1 : (z == 1) ? W2 : (z == 2) ? Wc1 : Wc2;
    ushort_t* out   = (z == 0) ? W1t : (z == 1) ? W2t : (z == 2) ? Wc1t : Wc2t;
    const int R = (z == 2) ? 1024 : 512;
    const int C = 512;
    const int c0 = blockIdx.x * 32, r0 = blockIdx.y * 32;
    if (r0 >= R) return;
    const int tx = threadIdx.x & 31, ty = threadIdx.x >> 5;
    #pragma unroll
    for (int p = 0; p < 4; ++p)
        t[ty + p * 8][tx] = in[(size_t)(r0 + ty + p * 8) * C + c0 + tx];
    __syncthreads();
    #pragma unroll
    for (int p = 0; p < 4; ++p)
        out[(size_t)(c0 + ty + p * 8) * R + r0 + tx] = f2bf(t[tx][ty + p * 8]);
}

// one wave per row: max + 1/sum(exp)
__global__ __launch_bounds__(256)
void row_stats(const float* __restrict__ o, float* __restrict__ rmax,
               float* __restrict__ rsinv, int L)
{
    const int row  = blockIdx.x * 4 + (threadIdx.x >> 6);
    const int lane = threadIdx.x & 63;
    const float* p = o + (long)row * L;
    float m = -3.0e38f;
    for (int j = lane; j < L; j += 64) m = fmaxf(m, p[j]);
    #pragma unroll
    for (int off = 32; off > 0; off >>= 1) m = fmaxf(m, __shfl_xor(m, off));
    float s = 0.0f;
    for (int j = lane; j < L; j += 64) s += __expf(p[j] - m);
    #pragma unroll
    for (int off = 32; off > 0; off >>= 1) s += __shfl_xor(s, off);
    if (lane == 0) { rmax[row] = m; rsinv[row] = 1.0f / s; }
}

// column stats phase 1: each block scans 64 rows for 256 columns (split-K)
__global__ __launch_bounds__(256)
void col_part(const float* __restrict__ o, float* __restrict__ pm,
              float* __restrict__ ps, int L)
{
    const int b  = blockIdx.z;
    const int rc = blockIdx.y;
    const int j  = blockIdx.x * 256 + threadIdx.x;
    const float* p = o + (long)b * L * L + (long)rc * 64 * L + j;
    float m = -3.0e38f, s = 0.0f;
    #pragma unroll 4
    for (int i = 0; i < 64; ++i) {
        const float x = p[(long)i * L];
        const float mn = fmaxf(m, x);
        s = s * __expf(m - mn) + __expf(x - mn);
        m = mn;
    }
    const long idx = ((long)b * 8 + rc) * L + j;
    pm[idx] = m;
    ps[idx] = s;
}

// column stats phase 2: merge 8 partials per column
__global__ __launch_bounds__(256)
void col_combine(const float* __restrict__ pm, const float* __restrict__ ps,
                 float* __restrict__ cmax, float* __restrict__ csinv, int L)
{
    const int b = blockIdx.y;
    const int j = blockIdx.x * 256 + threadIdx.x;
    float mk[8], sk[8];
    #pragma unroll
    for (int k = 0; k < 8; ++k) {
        mk[k] = pm[((long)b * 8 + k) * L + j];
        sk[k] = ps[((long)b * 8 + k) * L + j];
    }
    float m = -3.0e38f;
    #pragma unroll
    for (int k = 0; k < 8; ++k) m = fmaxf(m, mk[k]);
    float s = 0.0f;
    #pragma unroll
    for (int k = 0; k < 8; ++k) s += sk[k] * __expf(mk[k] - m);
    cmax[b * L + j]  = m;
    csinv[b * L + j] = 1.0f / s;
}

// tiled: o1[b,i,j] = rowsm * mpos (bf16), o2T[b,j,i] = colsm * mpos (bf16)
__global__ __launch_bounds__(256)
void softmax_apply(const float* __restrict__ o,
                   ushort_t* __restrict__ o1, ushort_t* __restrict__ o2T,
                   const float* __restrict__ rmax, const float* __restrict__ rsinv,
                   const float* __restrict__ cmax, const float* __restrict__ csinv,
                   const int* __restrict__ m1, const int* __restrict__ m2)
{
    __shared__ ushort_t t[32][33];
    const int b = blockIdx.z;
    const long bo = (long)b * 512 * 512;
    const int j0 = blockIdx.x * 32, i0 = blockIdx.y * 32;
    const int tx = threadIdx.x & 31, ty = threadIdx.x >> 5;
    const int col = b * 512 + j0 + tx;
    const int mjv = m2[col];
    const float cm = cmax[col], cs = csinv[col];
    #pragma unroll
    for (int p = 0; p < 4; ++p) {
        const int i = i0 + ty + p * 8;
        const int row = b * 512 + i;
        const float x = o[bo + (long)i * 512 + j0 + tx];
        const float mp = (m1[row] != 0 && mjv != 0) ? 1.0f : 0.0f;
        o1[bo + (long)i * 512 + j0 + tx] = f2bf(__expf(x - rmax[row]) * rsinv[row] * mp);
        t[ty + p * 8][tx] = f2bf(__expf(x - cm) * cs * mp);
    }
    __syncthreads();
    #pragma unroll
    for (int p = 0; p < 4; ++p)
        o2T[bo + (long)(j0 + ty + p * 8) * 512 + i0 + tx] = t[tx][ty + p * 8];
}

// ---------------------------------------------------------------------------
extern "C" void kernel_launch(void* const* d_in, const int* in_sizes, int n_in,
                              void* d_out, int out_size, void* d_ws, size_t ws_size,
                              hipStream_t stream)
{
    const float* r1  = (const float*)d_in[0];
    const float* r2  = (const float*)d_in[1];
    const int*   m1  = (const int*)d_in[2];
    const int*   m2  = (const int*)d_in[3];
    const float* W1  = (const float*)d_in[4];
    const float* b1v = (const float*)d_in[5];
    const float* W2  = (const float*)d_in[6];
    const float* b2v = (const float*)d_in[7];
    const float* Wc1 = (const float*)d_in[8];
    const float* bc1 = (const float*)d_in[9];
    const float* Wc2 = (const float*)d_in[10];
    const float* bc2 = (const float*)d_in[11];
    float* out = (float*)d_out;

    constexpr int  Bn = 64, L = 512, D = 512;
    constexpr long CE = (long)Bn * L * D;  // 16,777,216 elements
    constexpr long S  = (long)L * L;       // 262,144
    constexpr int  NR = Bn * L;            // 32,768

    // d_out: 4 bf16 scratch slots (all dead before final fp32 writes)
    ushort_t* O    = (ushort_t*)d_out;
    ushort_t* r1b  = O;            // slot0: r1 bf16 (dead after GEMM 1)
    ushort_t* r2b  = O + CE;       // slot1: r2 bf16
    // After GEMM 2 (TWOUT slot-swapped): [slot0 | slot1] = [r2mT | r1mT],
    // uniform batch stride S from base O for the merged ctx GEMM.
    ushort_t* TT   = O;
    ushort_t* o1b  = O + 2 * CE;   // slot2: o1  (batches 0..63)
    // slot3 = o1b + CE = o2T (batches 64..127 of the same strided array)
    ushort_t* o2Tb = O + 3 * CE;

    // workspace
    char* wsb = (char*)d_ws;
    // R0 [0,4CE): h (2CE ushorts) -> obuf (CE floats) -> r1c‖r2c (2CE ushorts)
    ushort_t* hb   = (ushort_t*)wsb;
    float*    obuf = (float*)wsb;
    ushort_t* r1c  = (ushort_t*)wsb;
    // R1 [4CE,8CE): hc (compare hidden)
    ushort_t* hc   = (ushort_t*)(wsb + 4 * CE);
    // R2 [8CE,12CE): r1m ‖ r2m
    ushort_t* r1mb = (ushort_t*)(wsb + 8 * CE);
    ushort_t* r2mb = (ushort_t*)(wsb + 10 * CE);
    // R3 [12CE, ...): weights + stats
    ushort_t* W1t  = (ushort_t*)(wsb + 12 * CE);
    ushort_t* W2t  = W1t + 512 * 512;
    ushort_t* Wc1t = W2t + 512 * 512;            // [512,1024]
    ushort_t* Wc2t = Wc1t + 512 * 1024;
    float* rmaxv = (float*)(Wc2t + 512 * 512);
    float* rsinv = rmaxv + NR;
    float* cmaxv = rsinv + NR;
    float* csinv = cmaxv + NR;
    float* pmbuf = csinv + NR;                   // 8*512*64 floats
    float* psbuf = pmbuf + 8 * L * Bn;

    const dim3 blk(256);
    const dim3 gD2(D / 128, 2 * NR / 128, 1);    // combined dense: 4 x 512
    const dim3 gB(L / 128, L / 128, Bn);         // batched score: 4 x 4 x 64
    const dim3 gB2(L / 128, L / 128, 2 * Bn);    // merged ctx: 4 x 4 x 128

    // 0) convert inputs + weights
    cvt2_f32_bf16<<<dim3(CE / 1024, 2), blk, 0, stream>>>(r1, r2, r1b, r2b);
    transpose_cvt4<<<dim3(16, 32, 4), blk, 0, stream>>>(
        W1, W2, Wc1, Wc2, W1t, W2t, Wc1t, Wc2t);

    // 1) h = lrelu([r1;r2] @ W1 + b1)   M=65536
    gemm_nt<true,true,false,false,true,false><<<gD2, blk, 0, stream>>>(
        r1b, r1b, D, D, D, W1t, D, b1v, nullptr, nullptr, hb, D,
        nullptr, 0, 2 * NR, D, D, 0, 0, 0);
    // 2) [r1m;r2m] = lrelu(h @ W2 + b2) * mask  + fused transposed copies
    gemm_nt<true,true,true,false,true,true><<<gD2, blk, 0, stream>>>(
        hb, hb, D, D, D, W2t, D, b2v, m1, m2, r1mb, D,
        TT, NR, 2 * NR, D, D, 0, 0, 0);
    // 3) o = r1m @ r2m^T + pairmask  (batched fp32)
    gemm_nt<false,false,false,true,false,false><<<gB, blk, 0, stream>>>(
        r1mb, r1mb, D, D, D, r2mb, D, nullptr, m1, m2, obuf, L,
        nullptr, 0, L, L, D, S, S, S);
    // 4) softmax stats
    row_stats<<<dim3(NR / 4), blk, 0, stream>>>(obuf, rmaxv, rsinv, L);
    col_part<<<dim3(L / 256, 8, Bn), blk, 0, stream>>>(obuf, pmbuf, psbuf, L);
    col_combine<<<dim3(L / 256, Bn), blk, 0, stream>>>(pmbuf, psbuf, cmaxv, csinv, L);
    // 5) o1 (bf16) + o2^T (bf16)
    softmax_apply<<<dim3(16, 16, Bn), blk, 0, stream>>>(
        obuf, o1b, o2Tb, rmaxv, rsinv, cmaxv, csinv, m1, m2);
    // 6+7 merged) z<64: r1_c = o1 @ r2m^T-slots ; z>=64: r2_c = o2T @ r1m^T-slots
    gemm_nt<false,false,false,false,true,false><<<gB2, blk, 0, stream>>>(
        o1b, o1b, L, L, L, TT, L, nullptr, nullptr, nullptr, r1c, D,
        nullptr, 0, L, D, L, S, S, S);
    // 8) hc = lrelu(cat([r1m;r2m],[r1c;r2c]) @ Wc1 + bc1)  M=65536, K=1024
    gemm_nt<true,true,false,false,true,false><<<gD2, blk, 0, stream>>>(
        r1mb, r1c, D, D, D, Wc1t, 2 * D, bc1, nullptr, nullptr, hc, D,
        nullptr, 0, 2 * NR, D, 2 * D, 0, 0, 0);
    // 9) [out1;out2] = lrelu(hc @ Wc2 + bc2) * mask  (fp32, full d_out)
    gemm_nt<true,true,true,false,false,false><<<gD2, blk, 0, stream>>>(
        hc, hc, D, D, D, Wc2t, D, bc2, m1, m2, out, D,
        nullptr, NR, 2 * NR, D, D, 0, 0, 0);
}

// Round 4
// 610.089 us; speedup vs baseline: 1.1943x; 1.0850x over previous
//
#include <hip/hip_runtime.h>

#define LRELU_SLOPE 0.01f
#define NEG_BIG -1e10f

typedef unsigned short ushort_t;
typedef __bf16 bf16x8 __attribute__((ext_vector_type(8)));
typedef float f32x4 __attribute__((ext_vector_type(4)));

static __device__ __forceinline__ float lrelu_f(float x) {
    return x >= 0.0f ? x : LRELU_SLOPE * x;
}

static __device__ __forceinline__ ushort_t f2bf(float f) {
    unsigned int u = __float_as_uint(f);
    u += 0x7fffu + ((u >> 16) & 1u);
    return (ushort_t)(u >> 16);
}

static __device__ __forceinline__ void gld_lds16(const ushort_t* g, ushort_t* l) {
    __builtin_amdgcn_global_load_lds((const __attribute__((address_space(1))) void*)g,
                                     (__attribute__((address_space(3))) void*)l,
                                     16, 0, 0);
}

// ---------------------------------------------------------------------------
// NT bf16 MFMA GEMM: C[m,n] = epi( sum_k A[m,k] * B[n,k] )
// 256x256 tile, 8 waves (2M x 4N), BK=64, 16x16x32 MFMA; per-wave out 128x64.
// 8-phase-class schedule (m196/m201 structure): per K-tile, 4 phases of
// {ds_read quadrant frags || -> lgkmcnt(0) -> sched_barrier(0) ->
//  setprio(1) 16xMFMA setprio(0) -> barrier}. 64 MFMA per wave per K-tile.
// Double-buffered LDS (2 x 64KB). Stage of tile T+1 (8 gld_lds/wave) issued
// at the top of tile T, right after the tile-top vmcnt(0)+barrier:
//  - vmcnt(0)+barrier: ALL waves' cooperative stage of buf (tile T) landed
//    before any wave ds_reads it (gld_lds is per-wave staged, block-read).
//  - buf^1 write-safety: tile T-1's reads of buf^1 landed in regs before the
//    tile-top barrier (each phase drains lgkmcnt before its MFMA).
//  - loads get ~4 phases (~600-800cy) of cover before their vmcnt(0).
// LDS XOR-swizzle (BK=64: row=128B => all rows same bank w/o swizzle):
// row r's 16B-chunk c stored at position c ^ (r&7); staging achieves this by
// inverse-permuting the per-lane GLOBAL source chunk (gld_lds dest is linear,
// rule #21 both-sides-or-neither); ds_read applies the same XOR => frag reads
// are 2-way-conflict max (free).
// XCD-aware tile remap (R0, kept): lin -> (lin%8)*(nwg/8)+lin/8.
// RM mask: row < Mhalf ? rm1[row] : rm2[row-Mhalf]  (combined-M launches)
// PM mask: rm1[bz*M+row] && rm2[bz*N+col] else += NEG_BIG (batched score GEMM)
// TWOUT: also store bf16 transposed per-batch with slot swap:
//   CT[(((row>>9)+64)&127)*S + col*512 + (row&511)]  -> [r2mT | r1mT] order
// ---------------------------------------------------------------------------
template<bool BIAS, bool LRELU, bool RM, bool PM, bool BF16OUT, bool TWOUT>
__global__ __launch_bounds__(512, 2)
void gemm_nt(const ushort_t* __restrict__ A0, const ushort_t* __restrict__ A1,
             int Ksplit, int lda0, int lda1,
             const ushort_t* __restrict__ B, int ldb,
             const float* __restrict__ bias,
             const int* __restrict__ rm1, const int* __restrict__ rm2,
             void* __restrict__ C, int ldc,
             ushort_t* __restrict__ CT, int Mhalf,
             int M, int N, int K,
             long sA, long sB, long sC)
{
    __shared__ ushort_t lds[2][2][256 * 64];   // [buf][A/B][row*64 + k]

    // XCD-aware block remap (see header comment)
    const unsigned nbx = gridDim.x, nby = gridDim.y;
    unsigned lin = blockIdx.x + nbx * (blockIdx.y + nby * blockIdx.z);
    const unsigned nwg = nbx * nby * gridDim.z;
    if ((nwg & 7u) == 0u)
        lin = (lin & 7u) * (nwg >> 3) + (lin >> 3);
    const unsigned bxs = lin % nbx;
    const unsigned t1  = lin / nbx;
    const unsigned bys = t1 % nby;
    const unsigned bzs = t1 / nby;

    const int bz   = (int)bzs;
    const int tid  = threadIdx.x;
    const int w    = tid >> 6;         // 0..7
    const int lane = tid & 63;
    const int wm   = w >> 2;           // 0..1  (M half)
    const int wn   = w & 3;            // 0..3  (N quarter)
    const int row0 = (int)bys * 256;
    const int col0 = (int)bxs * 256;

    const ushort_t* Ab0 = A0 + (long)bz * sA;
    const ushort_t* Ab1 = A1 + (long)bz * sA;
    const ushort_t* Bb  = B  + (long)bz * sB;

    // staging geometry: wave stages rows [w*32, w*32+32) of each 256-row tile,
    // 4 gld_lds per operand (8 rows each); per-lane source chunk inverse-swizzled
    const int sr = w * 32 + (lane >> 3);
    const int so = (((lane & 7) ^ ((lane >> 3) & 7)) * 8);

    // fragment read addressing
    const int lr = lane & 15, q = lane >> 4;
    const int cx0 = ((q ^ (lr & 7)) * 8);          // kk=0 chunk, swizzled
    const int cx1 = (((q + 4) ^ (lr & 7)) * 8);    // kk=1 chunk, swizzled
    const int aRow = (wm * 128 + lr) * 64;
    const int bRow = (wn * 64 + lr) * 64;

    f32x4 acc[8][4] = {};

    auto stage = [&](int T, int buf) {
        const int k0g = T << 6;
        const ushort_t* Ap; int kk0, ldaP;
        if (k0g < Ksplit) { Ap = Ab0; kk0 = k0g;          ldaP = lda0; }
        else              { Ap = Ab1; kk0 = k0g - Ksplit; ldaP = lda1; }
        ushort_t* Ad = &lds[buf][0][0];
        ushort_t* Bd = &lds[buf][1][0];
        #pragma unroll
        for (int u = 0; u < 4; ++u)
            gld_lds16(Ap + (size_t)(row0 + sr + u * 8) * ldaP + kk0 + so,
                      Ad + (w * 32 + u * 8) * 64);
        #pragma unroll
        for (int u = 0; u < 4; ++u)
            gld_lds16(Bb + (size_t)(col0 + sr + u * 8) * ldb + k0g + so,
                      Bd + (w * 32 + u * 8) * 64);
    };

    const int NT = K >> 6;
    stage(0, 0);

    for (int T = 0; T < NT; ++T) {
        const int buf = T & 1;
        // own stage-T loads done; barrier => ALL waves' stage-T loads done
        asm volatile("s_waitcnt vmcnt(0)" ::: "memory");
        __builtin_amdgcn_s_barrier();
        if (T + 1 < NT) stage(T + 1, buf ^ 1);

        const ushort_t* Abuf = &lds[buf][0][0];
        const ushort_t* Bbuf = &lds[buf][1][0];

        bf16x8 af[4][2], bf[2][2];
        #pragma unroll
        for (int p = 0; p < 4; ++p) {
            const int mh = p >> 1, nh = p & 1;
            if (nh == 0) {
                #pragma unroll
                for (int ii = 0; ii < 4; ++ii) {
                    const int rb = aRow + (mh * 64 + ii * 16) * 64;
                    af[ii][0] = *reinterpret_cast<const bf16x8*>(&Abuf[rb + cx0]);
                    af[ii][1] = *reinterpret_cast<const bf16x8*>(&Abuf[rb + cx1]);
                }
            }
            #pragma unroll
            for (int jj = 0; jj < 2; ++jj) {
                const int rb = bRow + (nh * 32 + jj * 16) * 64;
                bf[jj][0] = *reinterpret_cast<const bf16x8*>(&Bbuf[rb + cx0]);
                bf[jj][1] = *reinterpret_cast<const bf16x8*>(&Bbuf[rb + cx1]);
            }
            asm volatile("s_waitcnt lgkmcnt(0)" ::: "memory");
            __builtin_amdgcn_sched_barrier(0);
            __builtin_amdgcn_s_setprio(1);
            #pragma unroll
            for (int ii = 0; ii < 4; ++ii)
                #pragma unroll
                for (int jj = 0; jj < 2; ++jj)
                    #pragma unroll
                    for (int kk = 0; kk < 2; ++kk)
                        acc[mh * 4 + ii][nh * 2 + jj] =
                            __builtin_amdgcn_mfma_f32_16x16x32_bf16(
                                af[ii][kk], bf[jj][kk],
                                acc[mh * 4 + ii][nh * 2 + jj], 0, 0, 0);
            __builtin_amdgcn_s_setprio(0);
            if (p < 3) __builtin_amdgcn_s_barrier();
        }
    }

    float biasv[4];
    int mj[4];
    #pragma unroll
    for (int j = 0; j < 4; ++j) {
        const int c = col0 + wn * 64 + j * 16 + lr;
        if (BIAS) biasv[j] = bias[c];
        if (PM)   mj[j] = rm2[(long)bz * N + c];
    }
    float* Cf = (float*)C + (long)bz * sC;
    ushort_t* Ch = (ushort_t*)C + (long)bz * sC;

    #pragma unroll
    for (int i = 0; i < 8; ++i) {
        const int rg0 = row0 + wm * 128 + i * 16 + q * 4;   // first of 4 consecutive rows
        int mi4[4];
        if (RM || PM) {
            #pragma unroll
            for (int r = 0; r < 4; ++r) {
                const int row = rg0 + r;
                if (PM)      mi4[r] = rm1[(long)bz * M + row];
                else         mi4[r] = (row < Mhalf) ? rm1[row] : rm2[row - Mhalf];
            }
        }
        #pragma unroll
        for (int j = 0; j < 4; ++j) {
            const int c = col0 + wn * 64 + j * 16 + lr;
            ushort_t tp[4];
            #pragma unroll
            for (int r = 0; r < 4; ++r) {
                const int row = rg0 + r;
                float v = acc[i][j][r];
                if (BIAS) v += biasv[j];
                if (LRELU) v = lrelu_f(v);
                if (RM) v *= (float)mi4[r];
                if (PM) { if (!(mi4[r] && mj[j])) v += NEG_BIG; }
                const size_t a = (size_t)row * ldc + c;
                if (BF16OUT) Ch[a] = f2bf(v); else Cf[a] = v;
                if (TWOUT) tp[r] = f2bf(v);
            }
            if (TWOUT) {
                // slot-swapped: r1 batches -> slots 64..127, r2 batches -> 0..63
                const size_t ta = ((size_t)(((rg0 >> 9) + 64) & 127)) * 262144
                                + (size_t)c * 512 + (rg0 & 511);
                *reinterpret_cast<uint2*>(CT + ta) = *reinterpret_cast<uint2*>(tp);
            }
        }
    }
}

// ---------------------------------------------------------------------------
// fp32 -> bf16 convert for both inputs (y selects tensor)
__global__ __launch_bounds__(256)
void cvt2_f32_bf16(const float* __restrict__ a, const float* __restrict__ b,
                   ushort_t* __restrict__ oa, ushort_t* __restrict__ ob)
{
    const float* in = blockIdx.y ? b : a;
    ushort_t* out = blockIdx.y ? ob : oa;
    const long i = ((long)blockIdx.x * 256 + threadIdx.x) * 4;
    const float4 v = *reinterpret_cast<const float4*>(in + i);
    ushort_t o[4] = { f2bf(v.x), f2bf(v.y), f2bf(v.z), f2bf(v.w) };
    *reinterpret_cast<uint2*>(out + i) = *reinterpret_cast<uint2*>(o);
}

// all 4 weight transposes in one launch: fp32 [R,C] -> bf16 [C,R], z selects
__global__ __launch_bounds__(256)
void transpose_cvt4(const float* __restrict__ W1, const float* __restrict__ W2,
                    const float* __restrict__ Wc1, const float* __restrict__ Wc2,
                    ushort_t* __restrict__ W1t, ushort_t* __restrict__ W2t,
                    ushort_t* __restrict__ Wc1t, ushort_t* __restrict__ Wc2t)
{
    __shared__ float t[32][33];
    const int z = blockIdx.z;
    const float* in = (z == 0) ? W1 : (z == 1) ? W2 : (z == 2) ? Wc1 : Wc2;
    ushort_t* out   = (z == 0) ? W1t : (z == 1) ? W2t : (z == 2) ? Wc1t : Wc2t;
    const int R = (z == 2) ? 1024 : 512;
    const int C = 512;
    const int c0 = blockIdx.x * 32, r0 = blockIdx.y * 32;
    if (r0 >= R) return;
    const int tx = threadIdx.x & 31, ty = threadIdx.x >> 5;
    #pragma unroll
    for (int p = 0; p < 4; ++p)
        t[ty + p * 8][tx] = in[(size_t)(r0 + ty + p * 8) * C + c0 + tx];
    __syncthreads();
    #pragma unroll
    for (int p = 0; p < 4; ++p)
        out[(size_t)(c0 + ty + p * 8) * R + r0 + tx] = f2bf(t[tx][ty + p * 8]);
}

// one wave per row: max + 1/sum(exp)
__global__ __launch_bounds__(256)
void row_stats(const float* __restrict__ o, float* __restrict__ rmax,
               float* __restrict__ rsinv, int L)
{
    const int row  = blockIdx.x * 4 + (threadIdx.x >> 6);
    const int lane = threadIdx.x & 63;
    const float* p = o + (long)row * L;
    float m = -3.0e38f;
    for (int j = lane; j < L; j += 64) m = fmaxf(m, p[j]);
    #pragma unroll
    for (int off = 32; off > 0; off >>= 1) m = fmaxf(m, __shfl_xor(m, off));
    float s = 0.0f;
    for (int j = lane; j < L; j += 64) s += __expf(p[j] - m);
    #pragma unroll
    for (int off = 32; off > 0; off >>= 1) s += __shfl_xor(s, off);
    if (lane == 0) { rmax[row] = m; rsinv[row] = 1.0f / s; }
}

// column stats phase 1: each block scans 64 rows for 256 columns (split-K)
__global__ __launch_bounds__(256)
void col_part(const float* __restrict__ o, float* __restrict__ pm,
              float* __restrict__ ps, int L)
{
    const int b  = blockIdx.z;
    const int rc = blockIdx.y;
    const int j  = blockIdx.x * 256 + threadIdx.x;
    const float* p = o + (long)b * L * L + (long)rc * 64 * L + j;
    float m = -3.0e38f, s = 0.0f;
    #pragma unroll 4
    for (int i = 0; i < 64; ++i) {
        const float x = p[(long)i * L];
        const float mn = fmaxf(m, x);
        s = s * __expf(m - mn) + __expf(x - mn);
        m = mn;
    }
    const long idx = ((long)b * 8 + rc) * L + j;
    pm[idx] = m;
    ps[idx] = s;
}

// column stats phase 2: merge 8 partials per column
__global__ __launch_bounds__(256)
void col_combine(const float* __restrict__ pm, const float* __restrict__ ps,
                 float* __restrict__ cmax, float* __restrict__ csinv, int L)
{
    const int b = blockIdx.y;
    const int j = blockIdx.x * 256 + threadIdx.x;
    float mk[8], sk[8];
    #pragma unroll
    for (int k = 0; k < 8; ++k) {
        mk[k] = pm[((long)b * 8 + k) * L + j];
        sk[k] = ps[((long)b * 8 + k) * L + j];
    }
    float m = -3.0e38f;
    #pragma unroll
    for (int k = 0; k < 8; ++k) m = fmaxf(m, mk[k]);
    float s = 0.0f;
    #pragma unroll
    for (int k = 0; k < 8; ++k) s += sk[k] * __expf(mk[k] - m);
    cmax[b * L + j]  = m;
    csinv[b * L + j] = 1.0f / s;
}

// tiled: o1[b,i,j] = rowsm * mpos (bf16), o2T[b,j,i] = colsm * mpos (bf16)
__global__ __launch_bounds__(256)
void softmax_apply(const float* __restrict__ o,
                   ushort_t* __restrict__ o1, ushort_t* __restrict__ o2T,
                   const float* __restrict__ rmax, const float* __restrict__ rsinv,
                   const float* __restrict__ cmax, const float* __restrict__ csinv,
                   const int* __restrict__ m1, const int* __restrict__ m2)
{
    __shared__ ushort_t t[32][33];
    const int b = blockIdx.z;
    const long bo = (long)b * 512 * 512;
    const int j0 = blockIdx.x * 32, i0 = blockIdx.y * 32;
    const int tx = threadIdx.x & 31, ty = threadIdx.x >> 5;
    const int col = b * 512 + j0 + tx;
    const int mjv = m2[col];
    const float cm = cmax[col], cs = csinv[col];
    #pragma unroll
    for (int p = 0; p < 4; ++p) {
        const int i = i0 + ty + p * 8;
        const int row = b * 512 + i;
        const float x = o[bo + (long)i * 512 + j0 + tx];
        const float mp = (m1[row] != 0 && mjv != 0) ? 1.0f : 0.0f;
        o1[bo + (long)i * 512 + j0 + tx] = f2bf(__expf(x - rmax[row]) * rsinv[row] * mp);
        t[ty + p * 8][tx] = f2bf(__expf(x - cm) * cs * mp);
    }
    __syncthreads();
    #pragma unroll
    for (int p = 0; p < 4; ++p)
        o2T[bo + (long)(j0 + ty + p * 8) * 512 + i0 + tx] = t[tx][ty + p * 8];
}

// ---------------------------------------------------------------------------
extern "C" void kernel_launch(void* const* d_in, const int* in_sizes, int n_in,
                              void* d_out, int out_size, void* d_ws, size_t ws_size,
                              hipStream_t stream)
{
    const float* r1  = (const float*)d_in[0];
    const float* r2  = (const float*)d_in[1];
    const int*   m1  = (const int*)d_in[2];
    const int*   m2  = (const int*)d_in[3];
    const float* W1  = (const float*)d_in[4];
    const float* b1v = (const float*)d_in[5];
    const float* W2  = (const float*)d_in[6];
    const float* b2v = (const float*)d_in[7];
    const float* Wc1 = (const float*)d_in[8];
    const float* bc1 = (const float*)d_in[9];
    const float* Wc2 = (const float*)d_in[10];
    const float* bc2 = (const float*)d_in[11];
    float* out = (float*)d_out;

    constexpr int  Bn = 64, L = 512, D = 512;
    constexpr long CE = (long)Bn * L * D;  // 16,777,216 elements
    constexpr long S  = (long)L * L;       // 262,144
    constexpr int  NR = Bn * L;            // 32,768

    // d_out: 4 bf16 scratch slots (all dead before final fp32 writes)
    ushort_t* O    = (ushort_t*)d_out;
    ushort_t* r1b  = O;            // slot0: r1 bf16 (dead after GEMM 1)
    ushort_t* r2b  = O + CE;       // slot1: r2 bf16
    // After GEMM 2 (TWOUT slot-swapped): [slot0 | slot1] = [r2mT | r1mT],
    // uniform batch stride S from base O for the merged ctx GEMM.
    ushort_t* TT   = O;
    ushort_t* o1b  = O + 2 * CE;   // slot2: o1  (batches 0..63)
    // slot3 = o1b + CE = o2T (batches 64..127 of the same strided array)
    ushort_t* o2Tb = O + 3 * CE;

    // workspace
    char* wsb = (char*)d_ws;
    // R0 [0,4CE): h (2CE ushorts) -> obuf (CE floats) -> r1c‖r2c (2CE ushorts)
    ushort_t* hb   = (ushort_t*)wsb;
    float*    obuf = (float*)wsb;
    ushort_t* r1c  = (ushort_t*)wsb;
    // R1 [4CE,8CE): hc (compare hidden)
    ushort_t* hc   = (ushort_t*)(wsb + 4 * CE);
    // R2 [8CE,12CE): r1m ‖ r2m
    ushort_t* r1mb = (ushort_t*)(wsb + 8 * CE);
    ushort_t* r2mb = (ushort_t*)(wsb + 10 * CE);
    // R3 [12CE, ...): weights + stats
    ushort_t* W1t  = (ushort_t*)(wsb + 12 * CE);
    ushort_t* W2t  = W1t + 512 * 512;
    ushort_t* Wc1t = W2t + 512 * 512;            // [512,1024]
    ushort_t* Wc2t = Wc1t + 512 * 1024;
    float* rmaxv = (float*)(Wc2t + 512 * 512);
    float* rsinv = rmaxv + NR;
    float* cmaxv = rsinv + NR;
    float* csinv = cmaxv + NR;
    float* pmbuf = csinv + NR;                   // 8*512*64 floats
    float* psbuf = pmbuf + 8 * L * Bn;

    const dim3 blk(256);
    const dim3 blkG(512);
    const dim3 gD2(D / 256, 2 * NR / 256, 1);    // combined dense: 2 x 256
    const dim3 gB(L / 256, L / 256, Bn);         // batched score: 2 x 2 x 64
    const dim3 gB2(L / 256, L / 256, 2 * Bn);    // merged ctx: 2 x 2 x 128

    // 0) convert inputs + weights
    cvt2_f32_bf16<<<dim3(CE / 1024, 2), blk, 0, stream>>>(r1, r2, r1b, r2b);
    transpose_cvt4<<<dim3(16, 32, 4), blk, 0, stream>>>(
        W1, W2, Wc1, Wc2, W1t, W2t, Wc1t, Wc2t);

    // 1) h = lrelu([r1;r2] @ W1 + b1)   M=65536
    gemm_nt<true,true,false,false,true,false><<<gD2, blkG, 0, stream>>>(
        r1b, r1b, D, D, D, W1t, D, b1v, nullptr, nullptr, hb, D,
        nullptr, 0, 2 * NR, D, D, 0, 0, 0);
    // 2) [r1m;r2m] = lrelu(h @ W2 + b2) * mask  + fused transposed copies
    gemm_nt<true,true,true,false,true,true><<<gD2, blkG, 0, stream>>>(
        hb, hb, D, D, D, W2t, D, b2v, m1, m2, r1mb, D,
        TT, NR, 2 * NR, D, D, 0, 0, 0);
    // 3) o = r1m @ r2m^T + pairmask  (batched fp32)
    gemm_nt<false,false,false,true,false,false><<<gB, blkG, 0, stream>>>(
        r1mb, r1mb, D, D, D, r2mb, D, nullptr, m1, m2, obuf, L,
        nullptr, 0, L, L, D, S, S, S);
    // 4) softmax stats
    row_stats<<<dim3(NR / 4), blk, 0, stream>>>(obuf, rmaxv, rsinv, L);
    col_part<<<dim3(L / 256, 8, Bn), blk, 0, stream>>>(obuf, pmbuf, psbuf, L);
    col_combine<<<dim3(L / 256, Bn), blk, 0, stream>>>(pmbuf, psbuf, cmaxv, csinv, L);
    // 5) o1 (bf16) + o2^T (bf16)
    softmax_apply<<<dim3(16, 16, Bn), blk, 0, stream>>>(
        obuf, o1b, o2Tb, rmaxv, rsinv, cmaxv, csinv, m1, m2);
    // 6+7 merged) z<64: r1_c = o1 @ r2m^T-slots ; z>=64: r2_c = o2T @ r1m^T-slots
    gemm_nt<false,false,false,false,true,false><<<gB2, blkG, 0, stream>>>(
        o1b, o1b, L, L, L, TT, L, nullptr, nullptr, nullptr, r1c, D,
        nullptr, 0, L, D, L, S, S, S);
    // 8) hc = lrelu(cat([r1m;r2m],[r1c;r2c]) @ Wc1 + bc1)  M=65536, K=1024
    gemm_nt<true,true,false,false,true,false><<<gD2, blkG, 0, stream>>>(
        r1mb, r1c, D, D, D, Wc1t, 2 * D, bc1, nullptr, nullptr, hc, D,
        nullptr, 0, 2 * NR, D, 2 * D, 0, 0, 0);
    // 9) [out1;out2] = lrelu(hc @ Wc2 + bc2) * mask  (fp32, full d_out)
    gemm_nt<true,true,true,false,false,false><<<gD2, blkG, 0, stream>>>(
        hc, hc, D, D, D, Wc2t, D, bc2, m1, m2, out, D,
        nullptr, NR, 2 * NR, D, D, 0, 0, 0);
}

// Round 5
// 600.754 us; speedup vs baseline: 1.2128x; 1.0155x over previous
//
#include <hip/hip_runtime.h>

#define LRELU_SLOPE 0.01f
#define NEG_BIG -1e10f

typedef unsigned short ushort_t;
typedef __bf16 bf16x8 __attribute__((ext_vector_type(8)));
typedef float f32x4 __attribute__((ext_vector_type(4)));

static __device__ __forceinline__ float lrelu_f(float x) {
    return x >= 0.0f ? x : LRELU_SLOPE * x;
}

static __device__ __forceinline__ ushort_t f2bf(float f) {
    unsigned int u = __float_as_uint(f);
    u += 0x7fffu + ((u >> 16) & 1u);
    return (ushort_t)(u >> 16);
}

static __device__ __forceinline__ void gld_lds16(const ushort_t* g, ushort_t* l) {
    __builtin_amdgcn_global_load_lds((const __attribute__((address_space(1))) void*)g,
                                     (__attribute__((address_space(3))) void*)l,
                                     16, 0, 0);
}

// ---------------------------------------------------------------------------
// NT bf16 MFMA GEMM: C[m,n] = epi( sum_k A[m,k] * B[n,k] )
// 256x256 tile, 8 waves (2M x 4N), BK=64, 16x16x32 MFMA; per-wave out 128x64.
// T4 counted-vmcnt schedule (m218: counted-vs-drain0 = +38-73% inside 8-phase):
// staging is UNIT-ordered: 8 units per K-tile, 1 gld_lds/wave each, issue
// order B0,B1,B2,B3,A0,A2 | A1,A3 (sched_barrier(0) pins the 6/2 split).
// Unit u = 64 rows; wave w stages rows u*64+w*8..+8, so every wave's own
// vmcnt tracks the same unit set (cross-wave visibility via barrier).
// Per K-tile T:
//   vmcnt(2)  -> T's {B*,A0,A2} landed (A1,A3 may be pending; FIFO, m135)
//   s_barrier -> ALL waves' first-6 landed; then issue T+1's 8 loads
//   half 0 (mh=0: needs A0/A2 + B): 2x {ds_read frags, lgkmcnt(0),
//        sched_barrier(0), setprio(1), 16 MFMA, setprio(0)}
//   vmcnt(8)  -> T's A1,A3 landed; T+1's 8 stay in flight ACROSS barrier
//   s_barrier ; half 1 (mh=1: A1/A3 + B)
// 2 barriers + 2 counted waits per tile (R3 had 4 barriers + drain-0).
// Loads get ~1-1.5 K-tiles of latency cover; main loop never drains vmcnt.
// Hazards: stage(T+1) writes buf^1 (not read during T); buf overwrite at
// T+1 fenced by top barrier (tile-T reads consumed via MFMA data-dep).
// LDS XOR-swizzle: row r's 16B-chunk c stored at c ^ (r&7); staging inverse-
// permutes the per-lane GLOBAL source chunk (gld_lds dest linear, rule #21);
// ds_read applies the same XOR => conflict-free frag reads.
// XCD-aware tile remap (R0): lin -> (lin%8)*(nwg/8)+lin/8.
// RM mask: row < Mhalf ? rm1[row] : rm2[row-Mhalf]  (combined-M launches)
// PM mask: rm1[bz*M+row] && rm2[bz*N+col] else += NEG_BIG (batched score GEMM)
// TWOUT: also store bf16 transposed per-batch with slot swap:
//   CT[(((row>>9)+64)&127)*S + col*512 + (row&511)]  -> [r2mT | r1mT] order
// ---------------------------------------------------------------------------
template<bool BIAS, bool LRELU, bool RM, bool PM, bool BF16OUT, bool TWOUT>
__global__ __launch_bounds__(512, 2)
void gemm_nt(const ushort_t* __restrict__ A0, const ushort_t* __restrict__ A1,
             int Ksplit, int lda0, int lda1,
             const ushort_t* __restrict__ B, int ldb,
             const float* __restrict__ bias,
             const int* __restrict__ rm1, const int* __restrict__ rm2,
             void* __restrict__ C, int ldc,
             ushort_t* __restrict__ CT, int Mhalf,
             int M, int N, int K,
             long sA, long sB, long sC)
{
    __shared__ ushort_t lds[2][2][256 * 64];   // [buf][A/B][row*64 + k]

    // XCD-aware block remap (see header comment)
    const unsigned nbx = gridDim.x, nby = gridDim.y;
    unsigned lin = blockIdx.x + nbx * (blockIdx.y + nby * blockIdx.z);
    const unsigned nwg = nbx * nby * gridDim.z;
    if ((nwg & 7u) == 0u)
        lin = (lin & 7u) * (nwg >> 3) + (lin >> 3);
    const unsigned bxs = lin % nbx;
    const unsigned t1  = lin / nbx;
    const unsigned bys = t1 % nby;
    const unsigned bzs = t1 / nby;

    const int bz   = (int)bzs;
    const int tid  = threadIdx.x;
    const int w    = tid >> 6;         // 0..7
    const int lane = tid & 63;
    const int wm   = w >> 2;           // 0..1  (M half)
    const int wn   = w & 3;            // 0..3  (N quarter)
    const int row0 = (int)bys * 256;
    const int col0 = (int)bxs * 256;

    const ushort_t* Ab0 = A0 + (long)bz * sA;
    const ushort_t* Ab1 = A1 + (long)bz * sA;
    const ushort_t* Bb  = B  + (long)bz * sB;

    // unit-based staging: unit u = rows [u*64, u*64+64); wave w covers
    // rows u*64 + w*8 .. +8 with one gld_lds (64 lanes x 16B = 8 rows x 128B).
    // per-lane source chunk inverse-swizzled (row%8 == lane>>3).
    const int srr = w * 8 + (lane >> 3);
    const int so  = (((lane & 7) ^ ((lane >> 3) & 7)) * 8);

    // fragment read addressing
    const int lr = lane & 15, q = lane >> 4;
    const int cx0 = ((q ^ (lr & 7)) * 8);          // kk=0 chunk, swizzled
    const int cx1 = (((q + 4) ^ (lr & 7)) * 8);    // kk=1 chunk, swizzled
    const int aRow = (wm * 128 + lr) * 64;
    const int bRow = (wn * 64 + lr) * 64;

    f32x4 acc[8][4] = {};

    // stage one BK=64 K-tile, unit order B0,B1,B2,B3,A0,A2 | A1,A3
    auto stage = [&](int T, int buf) {
        const int k0g = T << 6;
        const ushort_t* Ap; int kk0, ldaP;
        if (k0g < Ksplit) { Ap = Ab0; kk0 = k0g;          ldaP = lda0; }
        else              { Ap = Ab1; kk0 = k0g - Ksplit; ldaP = lda1; }
        ushort_t* Ad = &lds[buf][0][0];
        ushort_t* Bd = &lds[buf][1][0];
        #pragma unroll
        for (int u = 0; u < 4; ++u)
            gld_lds16(Bb + (size_t)(col0 + u * 64 + srr) * ldb + k0g + so,
                      Bd + (u * 64 + w * 8) * 64);
        gld_lds16(Ap + (size_t)(row0 + 0 * 64 + srr) * ldaP + kk0 + so,
                  Ad + (0 * 64 + w * 8) * 64);
        gld_lds16(Ap + (size_t)(row0 + 2 * 64 + srr) * ldaP + kk0 + so,
                  Ad + (2 * 64 + w * 8) * 64);
        __builtin_amdgcn_sched_barrier(0);   // pin the 6/2 issue split
        gld_lds16(Ap + (size_t)(row0 + 1 * 64 + srr) * ldaP + kk0 + so,
                  Ad + (1 * 64 + w * 8) * 64);
        gld_lds16(Ap + (size_t)(row0 + 3 * 64 + srr) * ldaP + kk0 + so,
                  Ad + (3 * 64 + w * 8) * 64);
    };

    const int NT = K >> 6;
    stage(0, 0);

    for (int T = 0; T < NT; ++T) {
        const int buf = T & 1;
        const ushort_t* Abuf = &lds[buf][0][0];
        const ushort_t* Bbuf = &lds[buf][1][0];

        // top: first 6 units of tile T landed (leave A1,A3 pending)
        asm volatile("s_waitcnt vmcnt(2)" ::: "memory");
        __builtin_amdgcn_s_barrier();
        asm volatile("" ::: "memory");
        if (T + 1 < NT) stage(T + 1, buf ^ 1);

        #pragma unroll
        for (int mh = 0; mh < 2; ++mh) {
            if (mh == 1) {
                // A1,A3 of tile T landed; tile T+1's 8 stay in flight
                if (T + 1 < NT)
                    asm volatile("s_waitcnt vmcnt(8)" ::: "memory");
                else
                    asm volatile("s_waitcnt vmcnt(0)" ::: "memory");
                __builtin_amdgcn_s_barrier();
                asm volatile("" ::: "memory");
            }
            bf16x8 af[4][2], bf[2][2];
            #pragma unroll
            for (int ii = 0; ii < 4; ++ii) {
                const int rb = aRow + (mh * 64 + ii * 16) * 64;
                af[ii][0] = *reinterpret_cast<const bf16x8*>(&Abuf[rb + cx0]);
                af[ii][1] = *reinterpret_cast<const bf16x8*>(&Abuf[rb + cx1]);
            }
            #pragma unroll
            for (int nh = 0; nh < 2; ++nh) {
                #pragma unroll
                for (int jj = 0; jj < 2; ++jj) {
                    const int rb = bRow + (nh * 32 + jj * 16) * 64;
                    bf[jj][0] = *reinterpret_cast<const bf16x8*>(&Bbuf[rb + cx0]);
                    bf[jj][1] = *reinterpret_cast<const bf16x8*>(&Bbuf[rb + cx1]);
                }
                asm volatile("s_waitcnt lgkmcnt(0)" ::: "memory");
                __builtin_amdgcn_sched_barrier(0);
                __builtin_amdgcn_s_setprio(1);
                #pragma unroll
                for (int ii = 0; ii < 4; ++ii)
                    #pragma unroll
                    for (int jj = 0; jj < 2; ++jj)
                        #pragma unroll
                        for (int kk = 0; kk < 2; ++kk)
                            acc[mh * 4 + ii][nh * 2 + jj] =
                                __builtin_amdgcn_mfma_f32_16x16x32_bf16(
                                    af[ii][kk], bf[jj][kk],
                                    acc[mh * 4 + ii][nh * 2 + jj], 0, 0, 0);
                __builtin_amdgcn_s_setprio(0);
            }
        }
    }

    float biasv[4];
    int mj[4];
    #pragma unroll
    for (int j = 0; j < 4; ++j) {
        const int c = col0 + wn * 64 + j * 16 + lr;
        if (BIAS) biasv[j] = bias[c];
        if (PM)   mj[j] = rm2[(long)bz * N + c];
    }
    float* Cf = (float*)C + (long)bz * sC;
    ushort_t* Ch = (ushort_t*)C + (long)bz * sC;

    #pragma unroll
    for (int i = 0; i < 8; ++i) {
        const int rg0 = row0 + wm * 128 + i * 16 + q * 4;   // first of 4 consecutive rows
        int mi4[4];
        if (RM || PM) {
            #pragma unroll
            for (int r = 0; r < 4; ++r) {
                const int row = rg0 + r;
                if (PM)      mi4[r] = rm1[(long)bz * M + row];
                else         mi4[r] = (row < Mhalf) ? rm1[row] : rm2[row - Mhalf];
            }
        }
        #pragma unroll
        for (int j = 0; j < 4; ++j) {
            const int c = col0 + wn * 64 + j * 16 + lr;
            ushort_t tp[4];
            #pragma unroll
            for (int r = 0; r < 4; ++r) {
                const int row = rg0 + r;
                float v = acc[i][j][r];
                if (BIAS) v += biasv[j];
                if (LRELU) v = lrelu_f(v);
                if (RM) v *= (float)mi4[r];
                if (PM) { if (!(mi4[r] && mj[j])) v += NEG_BIG; }
                const size_t a = (size_t)row * ldc + c;
                if (BF16OUT) Ch[a] = f2bf(v); else Cf[a] = v;
                if (TWOUT) tp[r] = f2bf(v);
            }
            if (TWOUT) {
                // slot-swapped: r1 batches -> slots 64..127, r2 batches -> 0..63
                const size_t ta = ((size_t)(((rg0 >> 9) + 64) & 127)) * 262144
                                + (size_t)c * 512 + (rg0 & 511);
                *reinterpret_cast<uint2*>(CT + ta) = *reinterpret_cast<uint2*>(tp);
            }
        }
    }
}

// ---------------------------------------------------------------------------
// fp32 -> bf16 convert for both inputs (y selects tensor)
__global__ __launch_bounds__(256)
void cvt2_f32_bf16(const float* __restrict__ a, const float* __restrict__ b,
                   ushort_t* __restrict__ oa, ushort_t* __restrict__ ob)
{
    const float* in = blockIdx.y ? b : a;
    ushort_t* out = blockIdx.y ? ob : oa;
    const long i = ((long)blockIdx.x * 256 + threadIdx.x) * 4;
    const float4 v = *reinterpret_cast<const float4*>(in + i);
    ushort_t o[4] = { f2bf(v.x), f2bf(v.y), f2bf(v.z), f2bf(v.w) };
    *reinterpret_cast<uint2*>(out + i) = *reinterpret_cast<uint2*>(o);
}

// all 4 weight transposes in one launch: fp32 [R,C] -> bf16 [C,R], z selects
__global__ __launch_bounds__(256)
void transpose_cvt4(const float* __restrict__ W1, const float* __restrict__ W2,
                    const float* __restrict__ Wc1, const float* __restrict__ Wc2,
                    ushort_t* __restrict__ W1t, ushort_t* __restrict__ W2t,
                    ushort_t* __restrict__ Wc1t, ushort_t* __restrict__ Wc2t)
{
    __shared__ float t[32][33];
    const int z = blockIdx.z;
    const float* in = (z == 0) ? W1 : (z == 1) ? W2 : (z == 2) ? Wc1 : Wc2;
    ushort_t* out   = (z == 0) ? W1t : (z == 1) ? W2t : (z == 2) ? Wc1t : Wc2t;
    const int R = (z == 2) ? 1024 : 512;
    const int C = 512;
    const int c0 = blockIdx.x * 32, r0 = blockIdx.y * 32;
    if (r0 >= R) return;
    const int tx = threadIdx.x & 31, ty = threadIdx.x >> 5;
    #pragma unroll
    for (int p = 0; p < 4; ++p)
        t[ty + p * 8][tx] = in[(size_t)(r0 + ty + p * 8) * C + c0 + tx];
    __syncthreads();
    #pragma unroll
    for (int p = 0; p < 4; ++p)
        out[(size_t)(c0 + ty + p * 8) * R + r0 + tx] = f2bf(t[tx][ty + p * 8]);
}

// one wave per row: max + 1/sum(exp)
__global__ __launch_bounds__(256)
void row_stats(const float* __restrict__ o, float* __restrict__ rmax,
               float* __restrict__ rsinv, int L)
{
    const int row  = blockIdx.x * 4 + (threadIdx.x >> 6);
    const int lane = threadIdx.x & 63;
    const float* p = o + (long)row * L;
    float m = -3.0e38f;
    for (int j = lane; j < L; j += 64) m = fmaxf(m, p[j]);
    #pragma unroll
    for (int off = 32; off > 0; off >>= 1) m = fmaxf(m, __shfl_xor(m, off));
    float s = 0.0f;
    for (int j = lane; j < L; j += 64) s += __expf(p[j] - m);
    #pragma unroll
    for (int off = 32; off > 0; off >>= 1) s += __shfl_xor(s, off);
    if (lane == 0) { rmax[row] = m; rsinv[row] = 1.0f / s; }
}

// column stats phase 1: each block scans 64 rows for 256 columns (split-K)
__global__ __launch_bounds__(256)
void col_part(const float* __restrict__ o, float* __restrict__ pm,
              float* __restrict__ ps, int L)
{
    const int b  = blockIdx.z;
    const int rc = blockIdx.y;
    const int j  = blockIdx.x * 256 + threadIdx.x;
    const float* p = o + (long)b * L * L + (long)rc * 64 * L + j;
    float m = -3.0e38f, s = 0.0f;
    #pragma unroll 4
    for (int i = 0; i < 64; ++i) {
        const float x = p[(long)i * L];
        const float mn = fmaxf(m, x);
        s = s * __expf(m - mn) + __expf(x - mn);
        m = mn;
    }
    const long idx = ((long)b * 8 + rc) * L + j;
    pm[idx] = m;
    ps[idx] = s;
}

// column stats phase 2: merge 8 partials per column
__global__ __launch_bounds__(256)
void col_combine(const float* __restrict__ pm, const float* __restrict__ ps,
                 float* __restrict__ cmax, float* __restrict__ csinv, int L)
{
    const int b = blockIdx.y;
    const int j = blockIdx.x * 256 + threadIdx.x;
    float mk[8], sk[8];
    #pragma unroll
    for (int k = 0; k < 8; ++k) {
        mk[k] = pm[((long)b * 8 + k) * L + j];
        sk[k] = ps[((long)b * 8 + k) * L + j];
    }
    float m = -3.0e38f;
    #pragma unroll
    for (int k = 0; k < 8; ++k) m = fmaxf(m, mk[k]);
    float s = 0.0f;
    #pragma unroll
    for (int k = 0; k < 8; ++k) s += sk[k] * __expf(mk[k] - m);
    cmax[b * L + j]  = m;
    csinv[b * L + j] = 1.0f / s;
}

// tiled: o1[b,i,j] = rowsm * mpos (bf16), o2T[b,j,i] = colsm * mpos (bf16)
__global__ __launch_bounds__(256)
void softmax_apply(const float* __restrict__ o,
                   ushort_t* __restrict__ o1, ushort_t* __restrict__ o2T,
                   const float* __restrict__ rmax, const float* __restrict__ rsinv,
                   const float* __restrict__ cmax, const float* __restrict__ csinv,
                   const int* __restrict__ m1, const int* __restrict__ m2)
{
    __shared__ ushort_t t[32][33];
    const int b = blockIdx.z;
    const long bo = (long)b * 512 * 512;
    const int j0 = blockIdx.x * 32, i0 = blockIdx.y * 32;
    const int tx = threadIdx.x & 31, ty = threadIdx.x >> 5;
    const int col = b * 512 + j0 + tx;
    const int mjv = m2[col];
    const float cm = cmax[col], cs = csinv[col];
    #pragma unroll
    for (int p = 0; p < 4; ++p) {
        const int i = i0 + ty + p * 8;
        const int row = b * 512 + i;
        const float x = o[bo + (long)i * 512 + j0 + tx];
        const float mp = (m1[row] != 0 && mjv != 0) ? 1.0f : 0.0f;
        o1[bo + (long)i * 512 + j0 + tx] = f2bf(__expf(x - rmax[row]) * rsinv[row] * mp);
        t[ty + p * 8][tx] = f2bf(__expf(x - cm) * cs * mp);
    }
    __syncthreads();
    #pragma unroll
    for (int p = 0; p < 4; ++p)
        o2T[bo + (long)(j0 + ty + p * 8) * 512 + i0 + tx] = t[tx][ty + p * 8];
}

// ---------------------------------------------------------------------------
extern "C" void kernel_launch(void* const* d_in, const int* in_sizes, int n_in,
                              void* d_out, int out_size, void* d_ws, size_t ws_size,
                              hipStream_t stream)
{
    const float* r1  = (const float*)d_in[0];
    const float* r2  = (const float*)d_in[1];
    const int*   m1  = (const int*)d_in[2];
    const int*   m2  = (const int*)d_in[3];
    const float* W1  = (const float*)d_in[4];
    const float* b1v = (const float*)d_in[5];
    const float* W2  = (const float*)d_in[6];
    const float* b2v = (const float*)d_in[7];
    const float* Wc1 = (const float*)d_in[8];
    const float* bc1 = (const float*)d_in[9];
    const float* Wc2 = (const float*)d_in[10];
    const float* bc2 = (const float*)d_in[11];
    float* out = (float*)d_out;

    constexpr int  Bn = 64, L = 512, D = 512;
    constexpr long CE = (long)Bn * L * D;  // 16,777,216 elements
    constexpr long S  = (long)L * L;       // 262,144
    constexpr int  NR = Bn * L;            // 32,768

    // d_out: 4 bf16 scratch slots (all dead before final fp32 writes)
    ushort_t* O    = (ushort_t*)d_out;
    ushort_t* r1b  = O;            // slot0: r1 bf16 (dead after GEMM 1)
    ushort_t* r2b  = O + CE;       // slot1: r2 bf16
    // After GEMM 2 (TWOUT slot-swapped): [slot0 | slot1] = [r2mT | r1mT],
    // uniform batch stride S from base O for the merged ctx GEMM.
    ushort_t* TT   = O;
    ushort_t* o1b  = O + 2 * CE;   // slot2: o1  (batches 0..63)
    // slot3 = o1b + CE = o2T (batches 64..127 of the same strided array)
    ushort_t* o2Tb = O + 3 * CE;

    // workspace
    char* wsb = (char*)d_ws;
    // R0 [0,4CE): h (2CE ushorts) -> obuf (CE floats) -> r1c‖r2c (2CE ushorts)
    ushort_t* hb   = (ushort_t*)wsb;
    float*    obuf = (float*)wsb;
    ushort_t* r1c  = (ushort_t*)wsb;
    // R1 [4CE,8CE): hc (compare hidden)
    ushort_t* hc   = (ushort_t*)(wsb + 4 * CE);
    // R2 [8CE,12CE): r1m ‖ r2m
    ushort_t* r1mb = (ushort_t*)(wsb + 8 * CE);
    ushort_t* r2mb = (ushort_t*)(wsb + 10 * CE);
    // R3 [12CE, ...): weights + stats
    ushort_t* W1t  = (ushort_t*)(wsb + 12 * CE);
    ushort_t* W2t  = W1t + 512 * 512;
    ushort_t* Wc1t = W2t + 512 * 512;            // [512,1024]
    ushort_t* Wc2t = Wc1t + 512 * 1024;
    float* rmaxv = (float*)(Wc2t + 512 * 512);
    float* rsinv = rmaxv + NR;
    float* cmaxv = rsinv + NR;
    float* csinv = cmaxv + NR;
    float* pmbuf = csinv + NR;                   // 8*512*64 floats
    float* psbuf = pmbuf + 8 * L * Bn;

    const dim3 blk(256);
    const dim3 blkG(512);
    const dim3 gD2(D / 256, 2 * NR / 256, 1);    // combined dense: 2 x 256
    const dim3 gB(L / 256, L / 256, Bn);         // batched score: 2 x 2 x 64
    const dim3 gB2(L / 256, L / 256, 2 * Bn);    // merged ctx: 2 x 2 x 128

    // 0) convert inputs + weights
    cvt2_f32_bf16<<<dim3(CE / 1024, 2), blk, 0, stream>>>(r1, r2, r1b, r2b);
    transpose_cvt4<<<dim3(16, 32, 4), blk, 0, stream>>>(
        W1, W2, Wc1, Wc2, W1t, W2t, Wc1t, Wc2t);

    // 1) h = lrelu([r1;r2] @ W1 + b1)   M=65536
    gemm_nt<true,true,false,false,true,false><<<gD2, blkG, 0, stream>>>(
        r1b, r1b, D, D, D, W1t, D, b1v, nullptr, nullptr, hb, D,
        nullptr, 0, 2 * NR, D, D, 0, 0, 0);
    // 2) [r1m;r2m] = lrelu(h @ W2 + b2) * mask  + fused transposed copies
    gemm_nt<true,true,true,false,true,true><<<gD2, blkG, 0, stream>>>(
        hb, hb, D, D, D, W2t, D, b2v, m1, m2, r1mb, D,
        TT, NR, 2 * NR, D, D, 0, 0, 0);
    // 3) o = r1m @ r2m^T + pairmask  (batched fp32)
    gemm_nt<false,false,false,true,false,false><<<gB, blkG, 0, stream>>>(
        r1mb, r1mb, D, D, D, r2mb, D, nullptr, m1, m2, obuf, L,
        nullptr, 0, L, L, D, S, S, S);
    // 4) softmax stats
    row_stats<<<dim3(NR / 4), blk, 0, stream>>>(obuf, rmaxv, rsinv, L);
    col_part<<<dim3(L / 256, 8, Bn), blk, 0, stream>>>(obuf, pmbuf, psbuf, L);
    col_combine<<<dim3(L / 256, Bn), blk, 0, stream>>>(pmbuf, psbuf, cmaxv, csinv, L);
    // 5) o1 (bf16) + o2^T (bf16)
    softmax_apply<<<dim3(16, 16, Bn), blk, 0, stream>>>(
        obuf, o1b, o2Tb, rmaxv, rsinv, cmaxv, csinv, m1, m2);
    // 6+7 merged) z<64: r1_c = o1 @ r2m^T-slots ; z>=64: r2_c = o2T @ r1m^T-slots
    gemm_nt<false,false,false,false,true,false><<<gB2, blkG, 0, stream>>>(
        o1b, o1b, L, L, L, TT, L, nullptr, nullptr, nullptr, r1c, D,
        nullptr, 0, L, D, L, S, S, S);
    // 8) hc = lrelu(cat([r1m;r2m],[r1c;r2c]) @ Wc1 + bc1)  M=65536, K=1024
    gemm_nt<true,true,false,false,true,false><<<gD2, blkG, 0, stream>>>(
        r1mb, r1c, D, D, D, Wc1t, 2 * D, bc1, nullptr, nullptr, hc, D,
        nullptr, 0, 2 * NR, D, 2 * D, 0, 0, 0);
    // 9) [out1;out2] = lrelu(hc @ Wc2 + bc2) * mask  (fp32, full d_out)
    gemm_nt<true,true,true,false,false,false><<<gD2, blkG, 0, stream>>>(
        hc, hc, D, D, D, Wc2t, D, bc2, m1, m2, out, D,
        nullptr, NR, 2 * NR, D, D, 0, 0, 0);
}